// Round 1
// 1065.386 us; speedup vs baseline: 1.1379x; 1.1379x over previous
//
#include <hip/hip_runtime.h>

#define R 116
#define BATCH 1024
#define NL 4
#define RR2 13456          // R*R
#define EPSF 1e-5f
#define NZ_ELEM (BATCH * RR2)     // 13,778,944
#define NX_ELEM (BATCH * R * 3)   //    356,352
#define LS 136                    // LDS row stride (bf16 elems)
#define XZS 2336                  // XZ/cw1p K-stride: 2320 padded to 73*32
#define NSH 8                     // stat shards (atomic contention divider)
#define STL 464                   // NL*R stats stride

typedef unsigned short ushort_t;
typedef __attribute__((ext_vector_type(8))) short bf16x8;
typedef __attribute__((ext_vector_type(4))) float f32x4;

__device__ __forceinline__ float bf2f(unsigned short u){
  union { unsigned int i; float f; } v; v.i = ((unsigned int)u) << 16; return v.f;
}
__device__ __forceinline__ unsigned short f2bf(float f){
  union { float ff; unsigned int i; } v; v.ff = f;
  return (unsigned short)((v.i + 0x7fffu + ((v.i >> 16) & 1u)) >> 16);
}
__device__ __forceinline__ float wsum(float v){
  #pragma unroll
  for (int o = 32; o > 0; o >>= 1) v += __shfl_xor(v, o, 64);
  return v;
}
__device__ __forceinline__ float wmaxr(float v){
  #pragma unroll
  for (int o = 32; o > 0; o >>= 1) v = fmaxf(v, __shfl_xor(v, o, 64));
  return v;
}
// 16B bf16 fragment load from an 8B-aligned global address (Z rows have 232B stride)
__device__ __forceinline__ bf16x8 ldg_z8(const ushort_t* p){
  union { uint2 u2[2]; bf16x8 v; } c;
  c.u2[0] = *(const uint2*)p;
  c.u2[1] = *(const uint2*)(p + 4);
  return c.v;
}

// ---------------- init: Z fp32 -> bf16 ----------------
__global__ void k_initZ(const float4* __restrict__ src, uint4* __restrict__ dst, int n8){
  int idx = blockIdx.x * blockDim.x + threadIdx.x;
  int stride = gridDim.x * blockDim.x;
  for (int i = idx; i < n8; i += stride){
    float4 a = src[2*i], b = src[2*i+1];
    uint4 w;
    w.x = (unsigned)f2bf(a.x) | ((unsigned)f2bf(a.y) << 16);
    w.y = (unsigned)f2bf(a.z) | ((unsigned)f2bf(a.w) << 16);
    w.z = (unsigned)f2bf(b.x) | ((unsigned)f2bf(b.y) << 16);
    w.w = (unsigned)f2bf(b.z) | ((unsigned)f2bf(b.w) << 16);
    dst[i] = w;
  }
}

// ---------------- init: copy X fp32, zero stats, zero XZ, zero Z1 OOB-read guard ----------------
__global__ void k_initX(const float* __restrict__ src, float* __restrict__ dst, int n,
                        float* __restrict__ stats, int nstats,
                        unsigned* __restrict__ xzw, int nxzw,
                        unsigned* __restrict__ z1g, int nz1g){
  int idx = blockIdx.x * blockDim.x + threadIdx.x;
  int stride = gridDim.x * blockDim.x;
  for (int i = idx; i < n; i += stride) dst[i] = src[i];
  for (int i = idx; i < nstats; i += stride) stats[i] = 0.f;
  for (int i = idx; i < nxzw; i += stride) xzw[i] = 0u;
  for (int i = idx; i < nz1g; i += stride) z1g[i] = 0u;  // guard: graph 1023 row-tail reads
}

// ---------------- init: pack aw2^T / ew for MFMA (128x128, bf16, zero-padded) ----------------
__global__ void k_initW(const float* __restrict__ aw2, const float* __restrict__ ew,
                        ushort_t* __restrict__ aw2p, ushort_t* __restrict__ ewp){
  int idx = blockIdx.x * 256 + threadIdx.x;   // 4*128*128
  int l = idx >> 14, rem = idx & 16383, row = rem >> 7, col = rem & 127;
  ushort_t v = 0, w = 0;
  if (row < R && col < R){
    v = f2bf(aw2[l*RR2 + col*R + row]);   // aw2p[row][col] = aw2[col][row]  (aw2^T)
    w = f2bf(ew [l*RR2 + row*R + col]);   // ewp [row][col] = ew[row][col]
  }
  aw2p[idx] = v;
  ewp [idx] = w;
}

// ---------------- init: pack cw1 -> bf16 [n][k], K padded to XZS ----------------
__global__ void k_initC(const float* __restrict__ cw1, ushort_t* __restrict__ cw1p){
  int idx = blockIdx.x * 256 + threadIdx.x;
  if (idx >= 1024 * XZS) return;
  int n = idx / XZS, k = idx - n * XZS;
  cw1p[idx] = (k < 2320) ? f2bf(cw1[n*2320 + k]) : (ushort_t)0;
}

// ---------------- MFMA attention + edge/node update, 2-buffer LDS (2 blocks/CU) ----------------
// Associativity restructure: Z1 = M @ (Z @ ew^T).  Stages:
//   softmax -> P (bA);  A: W = P@aw2 (via W^T-product, transposed-packed write -> bB);
//   B': M^T = W @ Z^T (Z fragments straight from global; transposed write -> bA = M row-major);
//   E: E = Z @ ew^T (transposed write -> bB = E^T row-major);
//   D: Z1 = M @ E + eb -> global + stats;  X-path from bA (M) unchanged.
// bA aliases P->M, bB aliases W->E^T.  LDS = 79,104 B -> 2 blocks/CU (32 waves).
__launch_bounds__(1024, 8)
__global__ void k_attn(const float* __restrict__ Xc, const ushort_t* __restrict__ Zc,
                       ushort_t* __restrict__ Z1, float* __restrict__ X1,
                       const float* __restrict__ aw1, const float* __restrict__ ab1,
                       const ushort_t* __restrict__ aw2p, const float* __restrict__ ab2,
                       const float* __restrict__ nw,  const float* __restrict__ nb,
                       const ushort_t* __restrict__ ewp,  const float* __restrict__ eb,
                       float* __restrict__ zsumS, float* __restrict__ zsqS,
                       float* __restrict__ xsumS, float* __restrict__ xsqS, int layer)
{
  __shared__ ushort_t bA[128*LS];    // P, then M (row-major)
  __shared__ ushort_t bB[128*LS];    // W, then E^T (row-major)
  __shared__ float Ksm[3*R];
  __shared__ float ssm[R];
  __shared__ float xp[R*12];         // X-path partials [n][part][c]
  __shared__ float zps[128*2];       // per-row Z1 sum partials (2 col-halves)
  __shared__ float zpq[128*2];       // per-row Z1 sq partials

  const int b    = blockIdx.x;
  const int tid  = threadIdx.x;
  const int lane = tid & 63;
  const int wave = tid >> 6;          // 16 waves
  const int qm   = lane & 15;
  const int quad = lane >> 4;
  const int tr   = wave & 7;
  const int tc0  = (wave >> 3) * 4;

  const float*    Xb = Xc + (size_t)b * R * 3;
  const ushort_t* Zb = Zc + (size_t)b * RR2;
  const ushort_t* aw2l = aw2p + layer * 16384;
  const ushort_t* ewl  = ewp  + layer * 16384;
  const float* aw1l = aw1 + layer * 9;
  const float* ab1l = ab1 + layer * 3;
  const float* ab2l = ab2 + layer * R;
  const float* ebl  = eb  + layer * R;
  const float* nwl  = nw  + layer * 9;
  const float* nbl  = nb  + layer * 3;

  const f32x4 vzero = {0.f, 0.f, 0.f, 0.f};

  // phase 0: zero P pad strips of bA (rows 116-127 full; cols 116-135 of rows <116).
  // bB needs no zeroing: fully overwritten by stage A before first read; cols 128-135 never read.
  for (int i = tid; i < 12*LS; i += 1024) bA[116*LS + i] = 0;
  for (int i = tid; i < 116*20; i += 1024){
    int r = i/20, c = 116 + (i - r*20);
    bA[r*LS + c] = 0;
  }
  // K[o][n]
  if (tid < R){
    float x0 = Xb[tid*3+0], x1 = Xb[tid*3+1], x2 = Xb[tid*3+2];
    #pragma unroll
    for (int o = 0; o < 3; o++)
      Ksm[o*R + tid] = ab1l[o] + aw1l[o*3+0]*x0 + aw1l[o*3+1]*x1 + aw1l[o*3+2]*x2;
  }
  __syncthreads();

  // phase 1: softmax rows -> bA (P), ssm
  for (int n = wave; n < R; n += 16){
    float k0 = Ksm[n], k1 = Ksm[R+n], k2 = Ksm[2*R+n];
    int m0 = lane, m1 = lane + 64;
    float a0 = k0*Ksm[m0] + k1*Ksm[R+m0] + k2*Ksm[2*R+m0];
    float a1 = (m1 < R) ? (k0*Ksm[m1] + k1*Ksm[R+m1] + k2*Ksm[2*R+m1]) : -1e30f;
    float mx = wmaxr(fmaxf(a0, a1));
    float e0 = __expf(a0 - mx);
    float e1 = (m1 < R) ? __expf(a1 - mx) : 0.f;
    float sm = wsum(e0 + e1);
    float sab = wsum(e0 * ab2l[m0] + ((m1 < R) ? e1 * ab2l[m1] : 0.f));
    float inv = 1.f / sm;
    bA[n*LS + m0] = f2bf(e0 * inv);
    if (m1 < R) bA[n*LS + m1] = f2bf(e1 * inv);
    if (lane == 0) ssm[n] = sab * inv;
  }
  __syncthreads();

  // ---- Stage A: W^T-product = aw2^T @ P^T; transposed-packed write -> bB = W row-major ----
  {
    f32x4 acc[4];
    #pragma unroll
    for (int t = 0; t < 4; t++) acc[t] = vzero;
    for (int kk = 0; kk < 128; kk += 32){
      bf16x8 a = *(const bf16x8*)(aw2l + (tr*16 + qm)*128 + kk + quad*8);   // aw2^T row r
      #pragma unroll
      for (int t = 0; t < 4; t++){
        bf16x8 bf = *(const bf16x8*)&bA[((tc0 + t)*16 + qm)*LS + kk + quad*8]; // P row n'
        acc[t] = __builtin_amdgcn_mfma_f32_16x16x32_bf16(a, bf, acc[t], 0, 0, 0);
      }
    }
    // D(r, n') = W[n'][r]; write rows n', cols r0..r0+3 packed (8B, bank-conflict-free)
    const int r0 = tr*16 + quad*4;
    #pragma unroll
    for (int t = 0; t < 4; t++){
      int nn = (tc0 + t)*16 + qm;
      uint2 w;
      w.x = (unsigned)f2bf(acc[t][0]) | ((unsigned)f2bf(acc[t][1]) << 16);
      w.y = (unsigned)f2bf(acc[t][2]) | ((unsigned)f2bf(acc[t][3]) << 16);
      *(uint2*)&bB[nn*LS + r0] = w;
    }
  }
  __syncthreads();

  // ---- Stage B': M^T = W @ Z^T (+ssm); Z fragments from global; transposed write -> bA = M ----
  {
    f32x4 acc[4];
    #pragma unroll
    for (int t = 0; t < 4; t++) acc[t] = vzero;
    for (int kk = 0; kk < 128; kk += 32){
      bf16x8 a = *(const bf16x8*)&bB[(tr*16 + qm)*LS + kk + quad*8];        // W row r
      #pragma unroll
      for (int t = 0; t < 4; t++){
        int nn = (tc0 + t)*16 + qm;
        bf16x8 bf = ldg_z8(Zb + nn*R + kk + quad*8);                        // Z row nn (Z^T frag)
        acc[t] = __builtin_amdgcn_mfma_f32_16x16x32_bf16(a, bf, acc[t], 0, 0, 0);
      }
    }
    // D(r, nn) = M[nn][r]; += ssm[r] (r<116; W rows >=116 are zero so those stay zero)
    const int r0 = tr*16 + quad*4;
    float s0 = 0.f, s1 = 0.f, s2 = 0.f, s3 = 0.f;
    if (r0 < R){ s0 = ssm[r0]; s1 = ssm[r0+1]; s2 = ssm[r0+2]; s3 = ssm[r0+3]; }
    #pragma unroll
    for (int t = 0; t < 4; t++){
      int nn = (tc0 + t)*16 + qm;
      uint2 w;
      w.x = (unsigned)f2bf(acc[t][0] + s0) | ((unsigned)f2bf(acc[t][1] + s1) << 16);
      w.y = (unsigned)f2bf(acc[t][2] + s2) | ((unsigned)f2bf(acc[t][3] + s3) << 16);
      *(uint2*)&bA[nn*LS + r0] = w;
    }
  }
  __syncthreads();

  // ---- Stage E: E = Z @ ew^T; transposed write -> bB = E^T row-major (overwrites W) ----
  {
    f32x4 acc[4];
    #pragma unroll
    for (int t = 0; t < 4; t++) acc[t] = vzero;
    for (int kk = 0; kk < 128; kk += 32){
      bf16x8 a = ldg_z8(Zb + (tr*16 + qm)*R + kk + quad*8);                 // Z row m'
      #pragma unroll
      for (int t = 0; t < 4; t++){
        bf16x8 bf = *(const bf16x8*)(ewl + ((tc0 + t)*16 + qm)*128 + kk + quad*8); // ew row e
        acc[t] = __builtin_amdgcn_mfma_f32_16x16x32_bf16(a, bf, acc[t], 0, 0, 0);
      }
    }
    // D(m', e) = E[m'][e]; write bB[e][m'0..+3] packed -> E^T row-major
    const int r0 = tr*16 + quad*4;
    #pragma unroll
    for (int t = 0; t < 4; t++){
      int nn = (tc0 + t)*16 + qm;
      uint2 w;
      w.x = (unsigned)f2bf(acc[t][0]) | ((unsigned)f2bf(acc[t][1]) << 16);
      w.y = (unsigned)f2bf(acc[t][2]) | ((unsigned)f2bf(acc[t][3]) << 16);
      *(uint2*)&bB[nn*LS + r0] = w;
    }
  }
  __syncthreads();

  // ---- Stage D: Z1 = M @ E + eb -> global bf16; row stats -> LDS partials ----
  {
    f32x4 acc[4];
    #pragma unroll
    for (int t = 0; t < 4; t++) acc[t] = vzero;
    for (int kk = 0; kk < 128; kk += 32){
      bf16x8 a = *(const bf16x8*)&bA[(tr*16 + qm)*LS + kk + quad*8];        // M row m
      #pragma unroll
      for (int t = 0; t < 4; t++){
        bf16x8 bf = *(const bf16x8*)&bB[((tc0 + t)*16 + qm)*LS + kk + quad*8]; // E^T row n
        acc[t] = __builtin_amdgcn_mfma_f32_16x16x32_bf16(a, bf, acc[t], 0, 0, 0);
      }
    }
    float ssv[4] = {0.f,0.f,0.f,0.f}, sqv[4] = {0.f,0.f,0.f,0.f};
    #pragma unroll
    for (int t = 0; t < 4; t++){
      int col = (tc0 + t)*16 + qm;
      float bias = (col < R) ? ebl[col] : 0.f;
      #pragma unroll
      for (int rg = 0; rg < 4; rg++){
        int row = tr*16 + quad*4 + rg;
        float v = (col < R) ? (acc[t][rg] + bias) : 0.f;
        if (col < R && row < R)
          Z1[(size_t)b*RR2 + row*R + col] = f2bf(v);
        ssv[rg] += v; sqv[rg] += v*v;
      }
    }
    #pragma unroll
    for (int off = 1; off < 16; off <<= 1){
      #pragma unroll
      for (int rg = 0; rg < 4; rg++){
        ssv[rg] += __shfl_xor(ssv[rg], off, 64);
        sqv[rg] += __shfl_xor(sqv[rg], off, 64);
      }
    }
    if (qm == 0){
      int half = wave >> 3;
      #pragma unroll
      for (int rg = 0; rg < 4; rg++){
        int row = tr*16 + quad*4 + rg;
        zps[row*2 + half] = ssv[rg];
        zpq[row*2 + half] = sqv[rg];
      }
    }
  }

  // ---- X path partials: T1x = M @ X (M stable in bA) ----
  if (tid < R*4){
    int n = tid >> 2, part = tid & 3;
    float t0 = 0.f, t1 = 0.f, t2 = 0.f;
    for (int m = part; m < R; m += 4){
      float p = bf2f(bA[n*LS + m]);
      const float* xr = Xb + m*3;
      t0 += p*xr[0]; t1 += p*xr[1]; t2 += p*xr[2];
    }
    xp[tid*3+0] = t0; xp[tid*3+1] = t1; xp[tid*3+2] = t2;
  }
  __syncthreads();
  if (tid < R){
    float c0 = xp[tid*12+0] + xp[tid*12+3] + xp[tid*12+6] + xp[tid*12+9];
    float c1 = xp[tid*12+1] + xp[tid*12+4] + xp[tid*12+7] + xp[tid*12+10];
    float c2 = xp[tid*12+2] + xp[tid*12+5] + xp[tid*12+8] + xp[tid*12+11];
    float s = 0.f, q = 0.f;
    #pragma unroll
    for (int e = 0; e < 3; e++){
      float v = nbl[e] + c0*nwl[e*3+0] + c1*nwl[e*3+1] + c2*nwl[e*3+2];
      X1[((size_t)b*R + tid)*3 + e] = v;
      s += v; q += v*v;
    }
    int sh = b & (NSH-1);
    atomicAdd(&xsumS[sh*STL + layer*R + tid], s);
    atomicAdd(&xsqS [sh*STL + layer*R + tid], q);
    atomicAdd(&zsumS[sh*STL + layer*R + tid], zps[tid*2] + zps[tid*2+1]);
    atomicAdd(&zsqS [sh*STL + layer*R + tid], zpq[tid*2] + zpq[tid*2+1]);
  }
}

// ---------------- fused: BN+relu+residual on Z, then edge downsample ----------------
__launch_bounds__(256)
__global__ void k_bnzde(const ushort_t* __restrict__ Z1, ushort_t* __restrict__ Zc,
                        const float* __restrict__ zsumS, const float* __restrict__ zsqS,
                        const float* __restrict__ geg, const float* __restrict__ geb,
                        const float* __restrict__ dew, const float* __restrict__ deb,
                        ushort_t* __restrict__ XZ, float* __restrict__ deS, int layer)
{
  __shared__ float rb[64*121];
  __shared__ float wsm[78];
  __shared__ float reds[4], redq[4];
  const int tid = threadIdx.x;
  const int gr0 = blockIdx.x * 64;
  const int t = layer + 1;
  if (tid < 78) wsm[tid] = dew[t*78 + tid];
  const int row = tid >> 2, part = tid & 3;
  const int gr = gr0 + row;
  const int n = gr % R;
  const float cnt = (float)(BATCH * R);
  float ms = 0.f, qs = 0.f;
  #pragma unroll
  for (int s2 = 0; s2 < NSH; s2++){
    ms += zsumS[s2*STL + layer*R + n];
    qs += zsqS [s2*STL + layer*R + n];
  }
  float m  = ms / cnt;
  float va = fmaxf(qs / cnt - m*m, 0.f);
  float rs = rsqrtf(va + EPSF);
  float g  = geg[layer*R + n], be = geb[layer*R + n];
  const ushort_t* z1r = Z1 + (size_t)gr * R;
  ushort_t* zcr = Zc + (size_t)gr * R;
  #pragma unroll 4
  for (int i = 0; i < 29; i++){
    int c = part*29 + i;
    float val = fmaxf((bf2f(z1r[c]) - m)*rs*g + be, 0.f) + bf2f(zcr[c]);
    zcr[c] = f2bf(val);
    rb[row*121 + c] = val;
  }
  __syncthreads();
  int jlo = (part == 0) ? 39 : 0;
  int jhi = (part == 2) ? 77 : 78;
  if (part == 3){ jlo = 0; jhi = 0; }
  int off = (part - 1) * 39;
  float f = 0.f;
  for (int j = jlo; j < jhi; j++) f += wsm[j] * rb[row*121 + j + off];
  float s = 0.f, q = 0.f;
  if (part < 3){
    f = fmaxf(f + deb[t], 0.f);
    int bi = gr / R, r = gr - bi*R;
    XZ[(size_t)bi*XZS + 5*R + t*3*R + r*3 + part] = f2bf(f);
    s = f; q = f*f;
  }
  s = wsum(s); q = wsum(q);
  int lane = tid & 63, wv = tid >> 6;
  if (lane == 0){ reds[wv] = s; redq[wv] = q; }
  __syncthreads();
  if (tid == 0){
    atomicAdd(&deS[t*2+0], reds[0]+reds[1]+reds[2]+reds[3]);
    atomicAdd(&deS[t*2+1], redq[0]+redq[1]+redq[2]+redq[3]);
  }
}

// ---------------- fused: BN+relu+residual on X, then node downsample ----------------
__global__ void k_bnxdn(const float* __restrict__ X1, float* __restrict__ Xc,
                        const float* __restrict__ xsumS, const float* __restrict__ xsqS,
                        const float* __restrict__ gng, const float* __restrict__ gnb,
                        const float* __restrict__ dnw, const float* __restrict__ dnb,
                        ushort_t* __restrict__ XZ, float* __restrict__ dnS, int layer)
{
  int idx = blockIdx.x * 256 + threadIdx.x;    // BATCH*R
  int n = idx % R;
  const int t = layer + 1;
  const float cnt = (float)(BATCH * 3);
  float ms = 0.f, qs = 0.f;
  #pragma unroll
  for (int s2 = 0; s2 < NSH; s2++){
    ms += xsumS[s2*STL + layer*R + n];
    qs += xsqS [s2*STL + layer*R + n];
  }
  float m  = ms / cnt;
  float va = fmaxf(qs / cnt - m*m, 0.f);
  float rs = rsqrtf(va + EPSF);
  float g  = gng[layer*R + n], be = gnb[layer*R + n];
  float v[3];
  #pragma unroll
  for (int c = 0; c < 3; c++){
    float x = (X1[idx*3 + c] - m)*rs*g + be;
    v[c] = fmaxf(x, 0.f) + Xc[idx*3 + c];
    Xc[idx*3 + c] = v[c];
  }
  float f = fmaxf(dnw[t*3+0]*v[0] + dnw[t*3+1]*v[1] + dnw[t*3+2]*v[2] + dnb[t], 0.f);
  int bi = idx / R, r = idx - bi*R;
  XZ[(size_t)bi*XZS + t*R + r] = f2bf(f);
  float s = wsum(f), q = wsum(f*f);
  __shared__ float s1[4], s2m[4];
  int lane = threadIdx.x & 63, wv = threadIdx.x >> 6;
  if (lane == 0){ s1[wv] = s; s2m[wv] = q; }
  __syncthreads();
  if (threadIdx.x == 0){
    atomicAdd(&dnS[t*2+0], s1[0]+s1[1]+s1[2]+s1[3]);
    atomicAdd(&dnS[t*2+1], s2m[0]+s2m[1]+s2m[2]+s2m[3]);
  }
}

// ---------------- t=0 node downsample ----------------
__global__ void k_dnode0(const float* __restrict__ Xc, const float* __restrict__ dnw,
                         const float* __restrict__ dnb, ushort_t* __restrict__ XZ,
                         float* __restrict__ dnS){
  int idx = blockIdx.x * 256 + threadIdx.x;    // BATCH*R
  float f = fmaxf(dnw[0]*Xc[idx*3] + dnw[1]*Xc[idx*3+1] + dnw[2]*Xc[idx*3+2] + dnb[0], 0.f);
  int bi = idx / R, r = idx - bi*R;
  XZ[(size_t)bi*XZS + r] = f2bf(f);
  float s = wsum(f), q = wsum(f*f);
  __shared__ float s1[4], s2[4];
  int lane = threadIdx.x & 63, wv = threadIdx.x >> 6;
  if (lane == 0){ s1[wv] = s; s2[wv] = q; }
  __syncthreads();
  if (threadIdx.x == 0){
    atomicAdd(&dnS[0], s1[0]+s1[1]+s1[2]+s1[3]);
    atomicAdd(&dnS[1], s2[0]+s2[1]+s2[2]+s2[3]);
  }
}

// ---------------- t=0 edge downsample ----------------
__global__ void k_dedge0(const ushort_t* __restrict__ Zc, const float* __restrict__ dew,
                         const float* __restrict__ deb, ushort_t* __restrict__ XZ,
                         float* __restrict__ deS){
  __shared__ float wsm[78];
  if (threadIdx.x < 78) wsm[threadIdx.x] = dew[threadIdx.x];
  __syncthreads();
  int idx = blockIdx.x * 256 + threadIdx.x;    // BATCH*R
  const ushort_t* x = Zc + (size_t)idx * R;
  float bb = deb[0];
  float f0 = 0.f, f1 = 0.f, f2 = 0.f;
  for (int j = 0; j < 78; j++){
    float w = wsm[j];
    if (j >= 39) f0 += w * bf2f(x[j - 39]);
    f1 += w * bf2f(x[j]);
    if (j < 77)  f2 += w * bf2f(x[j + 39]);
  }
  f0 = fmaxf(f0 + bb, 0.f); f1 = fmaxf(f1 + bb, 0.f); f2 = fmaxf(f2 + bb, 0.f);
  int bi = idx / R, r = idx - bi*R;
  size_t base = (size_t)bi*XZS + 5*R + r*3;
  XZ[base+0] = f2bf(f0); XZ[base+1] = f2bf(f1); XZ[base+2] = f2bf(f2);
  float s = wsum(f0+f1+f2), q = wsum(f0*f0+f1*f1+f2*f2);
  __shared__ float s1[4], s2[4];
  int lane = threadIdx.x & 63, wv = threadIdx.x >> 6;
  if (lane == 0){ s1[wv] = s; s2[wv] = q; }
  __syncthreads();
  if (threadIdx.x == 0){
    atomicAdd(&deS[0], s1[0]+s1[1]+s1[2]+s1[3]);
    atomicAdd(&deS[1], s2[0]+s2[1]+s2[2]+s2[3]);
  }
}

// ---------------- apply BN (in place) to XZ feature slots for snapshot t ----------------
__global__ void k_apply(const float* __restrict__ dnS, const float* __restrict__ deS,
                        const float* __restrict__ dng, const float* __restrict__ dnbe,
                        const float* __restrict__ deg, const float* __restrict__ debe,
                        ushort_t* __restrict__ XZ, int t)
{
  int idx = blockIdx.x * 256 + threadIdx.x;    // BATCH*R
  int bi = idx / R, r = idx - bi*R;
  const float cn = (float)(BATCH * R);
  float mn = dnS[t*2+0] / cn;
  float vn = fmaxf(dnS[t*2+1] / cn - mn*mn, 0.f);
  size_t sn = (size_t)bi*XZS + t*R + r;
  float hn = (bf2f(XZ[sn]) - mn) * rsqrtf(vn + EPSF) * dng[t] + dnbe[t];
  XZ[sn] = f2bf(hn);
  const float ce = (float)(BATCH * R * 3);
  float me = deS[t*2+0] / ce;
  float ve = fmaxf(deS[t*2+1] / ce - me*me, 0.f);
  float rse = rsqrtf(ve + EPSF);
  size_t se = (size_t)bi*XZS + 5*R + t*3*R + r*3;
  #pragma unroll
  for (int p = 0; p < 3; p++){
    float he = (bf2f(XZ[se+p]) - me) * rse * deg[t] + debe[t];
    XZ[se+p] = f2bf(he);
  }
}

// ---------------- classifier: fc1 bf16 MFMA GEMM ----------------
__launch_bounds__(256)
__global__ void k_fc1(const ushort_t* __restrict__ XZ, const ushort_t* __restrict__ cw1p,
                      const float* __restrict__ cb1, float* __restrict__ H){
  const int tid  = threadIdx.x;
  const int lane = tid & 63;
  const int wave = tid >> 6;
  const int qm   = lane & 15;
  const int quad = lane >> 4;
  const int m0   = blockIdx.x * 64 + wave * 16;
  const int n0   = blockIdx.y * 64;

  const f32x4 vzero = {0.f, 0.f, 0.f, 0.f};
  f32x4 acc[4];
  #pragma unroll
  for (int t = 0; t < 4; t++) acc[t] = vzero;

  const ushort_t* arow = XZ + (size_t)(m0 + qm) * XZS;
  for (int kk = 0; kk < XZS; kk += 32){
    bf16x8 a = *(const bf16x8*)(arow + kk + quad*8);
    #pragma unroll
    for (int t = 0; t < 4; t++){
      const ushort_t* brow = cw1p + (size_t)(n0 + t*16 + qm) * XZS;
      bf16x8 bf = *(const bf16x8*)(brow + kk + quad*8);
      acc[t] = __builtin_amdgcn_mfma_f32_16x16x32_bf16(a, bf, acc[t], 0, 0, 0);
    }
  }
  #pragma unroll
  for (int t = 0; t < 4; t++){
    int n = n0 + t*16 + qm;
    float bias = cb1[n];
    #pragma unroll
    for (int rg = 0; rg < 4; rg++){
      int m = m0 + quad*4 + rg;
      H[(size_t)m * 1024 + n] = fmaxf(acc[t][rg] + bias, 0.f);
    }
  }
}

__global__ void k_fc2(const float* __restrict__ H, const float* __restrict__ cw2,
                      const float* __restrict__ cb2, float* __restrict__ out){
  int b = blockIdx.x, tid = threadIdx.x;
  float a0 = 0.f, a1 = 0.f;
  for (int j = tid; j < 1024; j += 256){
    float h = H[(size_t)b * 1024 + j];
    a0 += h * cw2[j];
    a1 += h * cw2[1024 + j];
  }
  a0 = wsum(a0); a1 = wsum(a1);
  __shared__ float s0[4], s1[4];
  int lane = tid & 63, wave = tid >> 6;
  if (lane == 0){ s0[wave] = a0; s1[wave] = a1; }
  __syncthreads();
  if (tid == 0){
    out[b*2 + 0] = s0[0]+s0[1]+s0[2]+s0[3] + cb2[0];
    out[b*2 + 1] = s1[0]+s1[1]+s1[2]+s1[3] + cb2[1];
  }
}

extern "C" void kernel_launch(void* const* d_in, const int* in_sizes, int n_in,
                              void* d_out, int out_size, void* d_ws, size_t ws_size,
                              hipStream_t stream)
{
  const float* Xin  = (const float*)d_in[0];
  const float* Zin  = (const float*)d_in[1];
  const float* aw1  = (const float*)d_in[2];
  const float* ab1  = (const float*)d_in[3];
  const float* aw2  = (const float*)d_in[4];
  const float* ab2  = (const float*)d_in[5];
  const float* nw   = (const float*)d_in[6];
  const float* nb   = (const float*)d_in[7];
  const float* ew   = (const float*)d_in[8];
  const float* eb   = (const float*)d_in[9];
  const float* gng  = (const float*)d_in[10];
  const float* gnb  = (const float*)d_in[11];
  const float* geg  = (const float*)d_in[12];
  const float* geb  = (const float*)d_in[13];
  const float* dnw  = (const float*)d_in[14];
  const float* dnb  = (const float*)d_in[15];
  const float* dng  = (const float*)d_in[16];
  const float* dnbe = (const float*)d_in[17];
  const float* dew  = (const float*)d_in[18];
  const float* deb  = (const float*)d_in[19];
  const float* deg  = (const float*)d_in[20];
  const float* debe = (const float*)d_in[21];
  const float* cw1  = (const float*)d_in[22];
  const float* cb1  = (const float*)d_in[23];
  const float* cw2  = (const float*)d_in[24];
  const float* cb2  = (const float*)d_in[25];

  // ---- workspace layout: TOTAL 67,856,512 B (unchanged) ----
  ushort_t* Zc = (ushort_t*)d_ws;            // bf16 Z state
  ushort_t* Z1 = Zc + NZ_ELEM;               // bf16 pre-BN Z1
  float*    H  = (float*)Z1;                 //   overlay: fc1 out (Z1 dead at fc1)
  float*    Xc = (float*)(Z1 + NZ_ELEM);     // fp32 X state
  float*    X1 = Xc + NX_ELEM;               // fp32 pre-BN X1
  ushort_t* XZ = (ushort_t*)(X1 + NX_ELEM);  // bf16 features (B,XZS)
  float*    st = (float*)(XZ + BATCH*XZS);   // stats: 14880 floats (sharded)
  ushort_t* aw2p = (ushort_t*)(st + 14880);
  ushort_t* ewp  = aw2p + 4*16384;
  ushort_t* cw1p = ewp + 4*16384;
  float* zsumS = st;               // [NSH][STL]
  float* zsqS  = st + 3712;
  float* xsumS = st + 7424;
  float* xsqS  = st + 11136;
  float* dnS   = st + 14848;       // [5][2]
  float* deS   = st + 14858;

  float* outp = (float*)d_out;

  // init (Z1 head zeroed: guard for k_attn's row-tail Z reads of graph 1023, layer 0)
  k_initZ<<<2048, 256, 0, stream>>>((const float4*)Zin, (uint4*)Zc, NZ_ELEM / 8);
  k_initX<<<1392, 256, 0, stream>>>(Xin, Xc, NX_ELEM, st, 14880,
                                    (unsigned*)XZ, BATCH*XZS/2, (unsigned*)Z1, 704);
  k_initW<<<256, 256, 0, stream>>>(aw2, ew, aw2p, ewp);
  k_initC<<<9344, 256, 0, stream>>>(cw1, cw1p);

  // t = 0 snapshots
  k_dnode0<<<464, 256, 0, stream>>>(Xc, dnw, dnb, XZ, dnS);
  k_dedge0<<<464, 256, 0, stream>>>(Zc, dew, deb, XZ, deS);
  k_apply<<<464, 256, 0, stream>>>(dnS, deS, dng, dnbe, deg, debe, XZ, 0);

  for (int i = 0; i < NL; i++){
    k_attn<<<BATCH, 1024, 0, stream>>>(Xc, Zc, Z1, X1, aw1, ab1, aw2p, ab2,
                                       nw, nb, ewp, eb, zsumS, zsqS, xsumS, xsqS, i);
    k_bnzde<<<1856, 256, 0, stream>>>(Z1, Zc, zsumS, zsqS, geg, geb,
                                      dew, deb, XZ, deS, i);
    k_bnxdn<<<464, 256, 0, stream>>>(X1, Xc, xsumS, xsqS, gng, gnb,
                                     dnw, dnb, XZ, dnS, i);
    k_apply<<<464, 256, 0, stream>>>(dnS, deS, dng, dnbe, deg, debe, XZ, i + 1);
  }

  k_fc1<<<dim3(16, 16), 256, 0, stream>>>(XZ, cw1p, cb1, H);
  k_fc2<<<BATCH, 256, 0, stream>>>(H, cw2, cb2, outp);
}

// Round 2
// 866.183 us; speedup vs baseline: 1.3995x; 1.2300x over previous
//
#include <hip/hip_runtime.h>

#define R 116
#define BATCH 1024
#define NL 4
#define RR2 13456          // R*R
#define EPSF 1e-5f
#define NZ_ELEM (BATCH * RR2)     // 13,778,944
#define NX_ELEM (BATCH * R * 3)   //    356,352
#define LS 136                    // LDS row stride (bf16 elems)
#define XZS 2336                  // XZ/cw1p K-stride: 2320 padded to 73*32
#define NSH 8                     // stat shards (atomic contention divider)
#define STL 464                   // NL*R stats stride

typedef unsigned short ushort_t;
typedef __attribute__((ext_vector_type(8))) short bf16x8;
typedef __attribute__((ext_vector_type(4))) float f32x4;

__device__ __forceinline__ float bf2f(unsigned short u){
  union { unsigned int i; float f; } v; v.i = ((unsigned int)u) << 16; return v.f;
}
__device__ __forceinline__ unsigned short f2bf(float f){
  union { float ff; unsigned int i; } v; v.ff = f;
  return (unsigned short)((v.i + 0x7fffu + ((v.i >> 16) & 1u)) >> 16);
}
__device__ __forceinline__ float wsum(float v){
  #pragma unroll
  for (int o = 32; o > 0; o >>= 1) v += __shfl_xor(v, o, 64);
  return v;
}
__device__ __forceinline__ float wmaxr(float v){
  #pragma unroll
  for (int o = 32; o > 0; o >>= 1) v = fmaxf(v, __shfl_xor(v, o, 64));
  return v;
}
// 16B bf16 fragment load from an 8B-aligned global address (Z rows have 232B stride)
__device__ __forceinline__ bf16x8 ldg_z8(const ushort_t* p){
  union { uint2 u2[2]; bf16x8 v; } c;
  c.u2[0] = *(const uint2*)p;
  c.u2[1] = *(const uint2*)(p + 4);
  return c.v;
}

// ---------------- init: Z fp32 -> bf16 ----------------
__global__ void k_initZ(const float4* __restrict__ src, uint4* __restrict__ dst, int n8){
  int idx = blockIdx.x * blockDim.x + threadIdx.x;
  int stride = gridDim.x * blockDim.x;
  for (int i = idx; i < n8; i += stride){
    float4 a = src[2*i], b = src[2*i+1];
    uint4 w;
    w.x = (unsigned)f2bf(a.x) | ((unsigned)f2bf(a.y) << 16);
    w.y = (unsigned)f2bf(a.z) | ((unsigned)f2bf(a.w) << 16);
    w.z = (unsigned)f2bf(b.x) | ((unsigned)f2bf(b.y) << 16);
    w.w = (unsigned)f2bf(b.z) | ((unsigned)f2bf(b.w) << 16);
    dst[i] = w;
  }
}

// ---------------- init: copy X fp32, zero stats, zero XZ, zero Z1 OOB-read guard ----------------
__global__ void k_initX(const float* __restrict__ src, float* __restrict__ dst, int n,
                        float* __restrict__ stats, int nstats,
                        unsigned* __restrict__ xzw, int nxzw,
                        unsigned* __restrict__ z1g, int nz1g){
  int idx = blockIdx.x * blockDim.x + threadIdx.x;
  int stride = gridDim.x * blockDim.x;
  for (int i = idx; i < n; i += stride) dst[i] = src[i];
  for (int i = idx; i < nstats; i += stride) stats[i] = 0.f;
  for (int i = idx; i < nxzw; i += stride) xzw[i] = 0u;
  for (int i = idx; i < nz1g; i += stride) z1g[i] = 0u;  // guard: graph 1023 row-tail reads
}

// ---------------- init: pack aw2^T / ew for MFMA (128x128, bf16, zero-padded) ----------------
__global__ void k_initW(const float* __restrict__ aw2, const float* __restrict__ ew,
                        ushort_t* __restrict__ aw2p, ushort_t* __restrict__ ewp){
  int idx = blockIdx.x * 256 + threadIdx.x;   // 4*128*128
  int l = idx >> 14, rem = idx & 16383, row = rem >> 7, col = rem & 127;
  ushort_t v = 0, w = 0;
  if (row < R && col < R){
    v = f2bf(aw2[l*RR2 + col*R + row]);   // aw2p[row][col] = aw2[col][row]  (aw2^T)
    w = f2bf(ew [l*RR2 + row*R + col]);   // ewp [row][col] = ew[row][col]
  }
  aw2p[idx] = v;
  ewp [idx] = w;
}

// ---------------- init: pack cw1 -> bf16 [n][k], K padded to XZS ----------------
__global__ void k_initC(const float* __restrict__ cw1, ushort_t* __restrict__ cw1p){
  int idx = blockIdx.x * 256 + threadIdx.x;
  if (idx >= 1024 * XZS) return;
  int n = idx / XZS, k = idx - n * XZS;
  cw1p[idx] = (k < 2320) ? f2bf(cw1[n*2320 + k]) : (ushort_t)0;
}

// ==================================================================================
// Fused per-layer kernel.  Block b owns graph b.
//   Prologue P0 (layer>0): BN+relu+residual of prev layer's Z1 -> Zc (vectorized),
//     staged into bB; same for X1 -> Xc (+ Ksm); bA pad-zero; wsm load.
//     (layer==0: stage raw Zc/Xc, no BN/writeback -> replaces t=0 downsample kernels)
//   P1: waves 0-9 softmax -> bA(P); waves 10-15 edge downsample from bB -> XZ + deS.
//   Then (with_attn): stages A..D as before (bB overwritten by W after sync2).
//   layer==NL && !with_attn: tail = BN/residual/downsample only (snapshot t=4).
// ==================================================================================
__launch_bounds__(1024, 8)
__global__ void k_fused(float* __restrict__ Xc, ushort_t* __restrict__ Zc,
                        ushort_t* __restrict__ Z1, float* __restrict__ X1,
                        const float* __restrict__ aw1, const float* __restrict__ ab1,
                        const ushort_t* __restrict__ aw2p, const float* __restrict__ ab2,
                        const float* __restrict__ nw,  const float* __restrict__ nb,
                        const ushort_t* __restrict__ ewp,  const float* __restrict__ eb,
                        float* __restrict__ zsumS, float* __restrict__ zsqS,
                        float* __restrict__ xsumS, float* __restrict__ xsqS,
                        const float* __restrict__ geg, const float* __restrict__ geb,
                        const float* __restrict__ gng, const float* __restrict__ gnb,
                        const float* __restrict__ dnw, const float* __restrict__ dnb,
                        const float* __restrict__ dew, const float* __restrict__ deb,
                        ushort_t* __restrict__ XZ,
                        float* __restrict__ dnS, float* __restrict__ deS,
                        int layer, int with_attn)
{
  __shared__ ushort_t bA[128*LS];    // P, then M (row-major)
  __shared__ ushort_t bB[128*LS];    // Zc_new staging, then W, then E^T
  __shared__ float Ksm[3*R];
  __shared__ float ssm[R];
  __shared__ float xp[R*12];         // X-path partials [n][part][c]
  __shared__ float zps[128*2];       // per-row Z1 sum partials
  __shared__ float zpq[128*2];
  __shared__ float wsm[78];          // edge downsample weights
  __shared__ float xsred[2], xqred[2];
  __shared__ float zds[8], zqs[8];

  const int b    = blockIdx.x;
  const int tid  = threadIdx.x;
  const int lane = tid & 63;
  const int wave = tid >> 6;          // 16 waves
  const int qm   = lane & 15;
  const int quad = lane >> 4;
  const int tr   = wave & 7;
  const int tc0  = (wave >> 3) * 4;
  const int t_snap = layer;           // snapshot index for downsample outputs

  const ushort_t* Zb = Zc + (size_t)b * RR2;
  const float* ab2l = ab2 + layer * R;
  const float* ebl  = eb  + layer * R;
  const float* nwl  = nw  + layer * 9;
  const float* nbl  = nb  + layer * 3;
  const ushort_t* aw2l = aw2p + layer * 16384;
  const ushort_t* ewl  = ewp  + layer * 16384;

  const f32x4 vzero = {0.f, 0.f, 0.f, 0.f};

  // =============== P0 ===============
  if (tid < 464){
    // Z prologue: 4 threads per row, vectorized uint2 (4 bf16) chunks
    const int r = tid >> 2, p = tid & 3;
    const int c0 = p * 32;
    const int nch = (p == 3) ? 5 : 8;
    const size_t rowoff = (size_t)b * RR2 + r * R + c0;
    ushort_t* zcr = Zc + rowoff;
    if (layer > 0){
      const int pl = layer - 1;
      float ms = 0.f, qs = 0.f;
      #pragma unroll
      for (int s2 = 0; s2 < NSH; s2++){
        ms += zsumS[s2*STL + pl*R + r];
        qs += zsqS [s2*STL + pl*R + r];
      }
      const float cnt = (float)(BATCH * R);
      float m  = ms / cnt;
      float va = fmaxf(qs / cnt - m*m, 0.f);
      float rs = rsqrtf(va + EPSF);
      float g  = geg[pl*R + r], be = geb[pl*R + r];
      const ushort_t* z1r = Z1 + rowoff;
      for (int ch = 0; ch < nch; ch++){
        uint2 zc2 = *(const uint2*)(zcr + ch*4);
        uint2 z12 = *(const uint2*)(z1r + ch*4);
        float v0 = fmaxf((bf2f((ushort_t)(z12.x & 0xffffu)) - m)*rs*g + be, 0.f) + bf2f((ushort_t)(zc2.x & 0xffffu));
        float v1 = fmaxf((bf2f((ushort_t)(z12.x >> 16))     - m)*rs*g + be, 0.f) + bf2f((ushort_t)(zc2.x >> 16));
        float v2 = fmaxf((bf2f((ushort_t)(z12.y & 0xffffu)) - m)*rs*g + be, 0.f) + bf2f((ushort_t)(zc2.y & 0xffffu));
        float v3 = fmaxf((bf2f((ushort_t)(z12.y >> 16))     - m)*rs*g + be, 0.f) + bf2f((ushort_t)(zc2.y >> 16));
        uint2 o;
        o.x = (unsigned)f2bf(v0) | ((unsigned)f2bf(v1) << 16);
        o.y = (unsigned)f2bf(v2) | ((unsigned)f2bf(v3) << 16);
        *(uint2*)(zcr + ch*4) = o;                 // residual state write-back
        *(uint2*)&bB[r*LS + c0 + ch*4] = o;        // stage for downsample
      }
    } else {
      for (int ch = 0; ch < nch; ch++){
        uint2 zc2 = *(const uint2*)(zcr + ch*4);
        *(uint2*)&bB[r*LS + c0 + ch*4] = zc2;      // raw Z for t=0 snapshot
      }
    }
  } else if (tid < 512){
    for (int j = tid - 464; j < 78; j += 48) wsm[j] = dew[t_snap*78 + j];
  } else if (tid < 640){
    // X prologue (waves 8,9): BN+relu+residual, Ksm, node downsample
    const int u = tid - 512;
    float fv = 0.f;
    if (u < R){
      float* xcr = Xc + ((size_t)b*R + u)*3;
      float v0, v1, v2;
      if (layer > 0){
        const int pl = layer - 1;
        float ms = 0.f, qs = 0.f;
        #pragma unroll
        for (int s2 = 0; s2 < NSH; s2++){
          ms += xsumS[s2*STL + pl*R + u];
          qs += xsqS [s2*STL + pl*R + u];
        }
        const float cnt = (float)(BATCH * 3);
        float m  = ms / cnt;
        float va = fmaxf(qs / cnt - m*m, 0.f);
        float rs = rsqrtf(va + EPSF);
        float g  = gng[pl*R + u], be = gnb[pl*R + u];
        const float* x1r = X1 + ((size_t)b*R + u)*3;
        v0 = fmaxf((x1r[0] - m)*rs*g + be, 0.f) + xcr[0];
        v1 = fmaxf((x1r[1] - m)*rs*g + be, 0.f) + xcr[1];
        v2 = fmaxf((x1r[2] - m)*rs*g + be, 0.f) + xcr[2];
        xcr[0] = v0; xcr[1] = v1; xcr[2] = v2;
      } else {
        v0 = xcr[0]; v1 = xcr[1]; v2 = xcr[2];
      }
      if (with_attn){
        const float* aw1l = aw1 + layer * 9;
        const float* ab1l = ab1 + layer * 3;
        #pragma unroll
        for (int o = 0; o < 3; o++)
          Ksm[o*R + u] = ab1l[o] + aw1l[o*3+0]*v0 + aw1l[o*3+1]*v1 + aw1l[o*3+2]*v2;
      }
      float f = fmaxf(dnw[t_snap*3+0]*v0 + dnw[t_snap*3+1]*v1 + dnw[t_snap*3+2]*v2 + dnb[t_snap], 0.f);
      XZ[(size_t)b*XZS + t_snap*R + u] = f2bf(f);
      fv = f;
    }
    float s = wsum(fv), q = wsum(fv*fv);
    if (lane == 0){ xsred[wave - 8] = s; xqred[wave - 8] = q; }
  } else {
    // bA pad zeroing (rows 116-127 full; cols 116-135 of rows <116)
    for (int i = tid - 640; i < 12*LS; i += 384) bA[116*LS + i] = 0;
    for (int i = tid - 640; i < 116*20; i += 384){
      int r = i/20, c = 116 + (i - r*20);
      bA[r*LS + c] = 0;
    }
  }
  __syncthreads();   // ---- sync1 ----

  // =============== P1: softmax (waves 0-9) || edge downsample (waves 10-15) ===============
  if (wave < 10){
    if (tid == 0){
      atomicAdd(&dnS[t_snap*2+0], xsred[0] + xsred[1]);
      atomicAdd(&dnS[t_snap*2+1], xqred[0] + xqred[1]);
    }
    if (with_attn){
      for (int n = wave; n < R; n += 10){
        float k0 = Ksm[n], k1 = Ksm[R+n], k2 = Ksm[2*R+n];
        int m0 = lane, m1 = lane + 64;
        float a0 = k0*Ksm[m0] + k1*Ksm[R+m0] + k2*Ksm[2*R+m0];
        float a1 = (m1 < R) ? (k0*Ksm[m1] + k1*Ksm[R+m1] + k2*Ksm[2*R+m1]) : -1e30f;
        float mx = wmaxr(fmaxf(a0, a1));
        float e0 = __expf(a0 - mx);
        float e1 = (m1 < R) ? __expf(a1 - mx) : 0.f;
        float sm = wsum(e0 + e1);
        float sab = wsum(e0 * ab2l[m0] + ((m1 < R) ? e1 * ab2l[m1] : 0.f));
        float inv = 1.f / sm;
        bA[n*LS + m0] = f2bf(e0 * inv);
        if (m1 < R) bA[n*LS + m1] = f2bf(e1 * inv);
        if (lane == 0) ssm[n] = sab * inv;
      }
    }
  } else {
    const int u = tid - 640;          // 0..383; 348 active
    float f = 0.f;
    if (u < 348){
      int r = u / 3, w = u - 3*r;
      int jlo = (w == 0) ? 39 : 0;
      int jhi = (w == 2) ? 77 : 78;
      int off = (w - 1) * 39;
      const ushort_t* vr = &bB[r*LS];
      float acc = 0.f;
      for (int j = jlo; j < jhi; j++) acc += wsm[j] * bf2f(vr[j + off]);
      f = fmaxf(acc + deb[t_snap], 0.f);
      XZ[(size_t)b*XZS + 5*R + t_snap*3*R + r*3 + w] = f2bf(f);
    }
    float s = wsum(f), q = wsum(f*f);
    if (lane == 0){ zds[wave - 10] = s; zqs[wave - 10] = q; }
  }
  __syncthreads();   // ---- sync2 ----

  if (tid == 0){
    float ss = 0.f, qq = 0.f;
    #pragma unroll
    for (int k = 0; k < 6; k++){ ss += zds[k]; qq += zqs[k]; }
    atomicAdd(&deS[t_snap*2+0], ss);
    atomicAdd(&deS[t_snap*2+1], qq);
  }
  if (!with_attn) return;

  // ---- Stage A: W^T-product = aw2^T @ P^T; transposed-packed write -> bB = W row-major ----
  {
    f32x4 acc[4];
    #pragma unroll
    for (int t = 0; t < 4; t++) acc[t] = vzero;
    for (int kk = 0; kk < 128; kk += 32){
      bf16x8 a = *(const bf16x8*)(aw2l + (tr*16 + qm)*128 + kk + quad*8);
      #pragma unroll
      for (int t = 0; t < 4; t++){
        bf16x8 bf = *(const bf16x8*)&bA[((tc0 + t)*16 + qm)*LS + kk + quad*8];
        acc[t] = __builtin_amdgcn_mfma_f32_16x16x32_bf16(a, bf, acc[t], 0, 0, 0);
      }
    }
    __syncthreads();   // ensure downsample reads of bB done before overwrite
    const int r0 = tr*16 + quad*4;
    #pragma unroll
    for (int t = 0; t < 4; t++){
      int nn = (tc0 + t)*16 + qm;
      uint2 w;
      w.x = (unsigned)f2bf(acc[t][0]) | ((unsigned)f2bf(acc[t][1]) << 16);
      w.y = (unsigned)f2bf(acc[t][2]) | ((unsigned)f2bf(acc[t][3]) << 16);
      *(uint2*)&bB[nn*LS + r0] = w;
    }
  }
  __syncthreads();

  // ---- Stage B': M^T = W @ Z^T (+ssm); Z fragments from global; transposed write -> bA = M ----
  {
    f32x4 acc[4];
    #pragma unroll
    for (int t = 0; t < 4; t++) acc[t] = vzero;
    for (int kk = 0; kk < 128; kk += 32){
      bf16x8 a = *(const bf16x8*)&bB[(tr*16 + qm)*LS + kk + quad*8];
      #pragma unroll
      for (int t = 0; t < 4; t++){
        int nn = (tc0 + t)*16 + qm;
        bf16x8 bf = ldg_z8(Zb + nn*R + kk + quad*8);
        acc[t] = __builtin_amdgcn_mfma_f32_16x16x32_bf16(a, bf, acc[t], 0, 0, 0);
      }
    }
    const int r0 = tr*16 + quad*4;
    float s0 = 0.f, s1 = 0.f, s2 = 0.f, s3 = 0.f;
    if (r0 < R){ s0 = ssm[r0]; s1 = ssm[r0+1]; s2 = ssm[r0+2]; s3 = ssm[r0+3]; }
    #pragma unroll
    for (int t = 0; t < 4; t++){
      int nn = (tc0 + t)*16 + qm;
      uint2 w;
      w.x = (unsigned)f2bf(acc[t][0] + s0) | ((unsigned)f2bf(acc[t][1] + s1) << 16);
      w.y = (unsigned)f2bf(acc[t][2] + s2) | ((unsigned)f2bf(acc[t][3] + s3) << 16);
      *(uint2*)&bA[nn*LS + r0] = w;
    }
  }
  __syncthreads();

  // ---- Stage E: E = Z @ ew^T; transposed write -> bB = E^T row-major (overwrites W) ----
  {
    f32x4 acc[4];
    #pragma unroll
    for (int t = 0; t < 4; t++) acc[t] = vzero;
    for (int kk = 0; kk < 128; kk += 32){
      bf16x8 a = ldg_z8(Zb + (tr*16 + qm)*R + kk + quad*8);
      #pragma unroll
      for (int t = 0; t < 4; t++){
        bf16x8 bf = *(const bf16x8*)(ewl + ((tc0 + t)*16 + qm)*128 + kk + quad*8);
        acc[t] = __builtin_amdgcn_mfma_f32_16x16x32_bf16(a, bf, acc[t], 0, 0, 0);
      }
    }
    const int r0 = tr*16 + quad*4;
    #pragma unroll
    for (int t = 0; t < 4; t++){
      int nn = (tc0 + t)*16 + qm;
      uint2 w;
      w.x = (unsigned)f2bf(acc[t][0]) | ((unsigned)f2bf(acc[t][1]) << 16);
      w.y = (unsigned)f2bf(acc[t][2]) | ((unsigned)f2bf(acc[t][3]) << 16);
      *(uint2*)&bB[nn*LS + r0] = w;
    }
  }
  __syncthreads();

  // ---- Stage D: Z1 = M @ E + eb -> global bf16; row stats -> LDS partials ----
  {
    f32x4 acc[4];
    #pragma unroll
    for (int t = 0; t < 4; t++) acc[t] = vzero;
    for (int kk = 0; kk < 128; kk += 32){
      bf16x8 a = *(const bf16x8*)&bA[(tr*16 + qm)*LS + kk + quad*8];
      #pragma unroll
      for (int t = 0; t < 4; t++){
        bf16x8 bf = *(const bf16x8*)&bB[((tc0 + t)*16 + qm)*LS + kk + quad*8];
        acc[t] = __builtin_amdgcn_mfma_f32_16x16x32_bf16(a, bf, acc[t], 0, 0, 0);
      }
    }
    float ssv[4] = {0.f,0.f,0.f,0.f}, sqv[4] = {0.f,0.f,0.f,0.f};
    #pragma unroll
    for (int t = 0; t < 4; t++){
      int col = (tc0 + t)*16 + qm;
      float bias = (col < R) ? ebl[col] : 0.f;
      #pragma unroll
      for (int rg = 0; rg < 4; rg++){
        int row = tr*16 + quad*4 + rg;
        float v = (col < R) ? (acc[t][rg] + bias) : 0.f;
        if (col < R && row < R)
          Z1[(size_t)b*RR2 + row*R + col] = f2bf(v);
        ssv[rg] += v; sqv[rg] += v*v;
      }
    }
    #pragma unroll
    for (int off = 1; off < 16; off <<= 1){
      #pragma unroll
      for (int rg = 0; rg < 4; rg++){
        ssv[rg] += __shfl_xor(ssv[rg], off, 64);
        sqv[rg] += __shfl_xor(sqv[rg], off, 64);
      }
    }
    if (qm == 0){
      int half = wave >> 3;
      #pragma unroll
      for (int rg = 0; rg < 4; rg++){
        int row = tr*16 + quad*4 + rg;
        zps[row*2 + half] = ssv[rg];
        zpq[row*2 + half] = sqv[rg];
      }
    }
  }

  // ---- X path partials: T1x = M @ X (M stable in bA) ----
  const float* Xb = Xc + (size_t)b * R * 3;
  if (tid < R*4){
    int n = tid >> 2, part = tid & 3;
    float t0 = 0.f, t1 = 0.f, t2 = 0.f;
    for (int m = part; m < R; m += 4){
      float p = bf2f(bA[n*LS + m]);
      const float* xr = Xb + m*3;
      t0 += p*xr[0]; t1 += p*xr[1]; t2 += p*xr[2];
    }
    xp[tid*3+0] = t0; xp[tid*3+1] = t1; xp[tid*3+2] = t2;
  }
  __syncthreads();
  if (tid < R){
    float c0 = xp[tid*12+0] + xp[tid*12+3] + xp[tid*12+6] + xp[tid*12+9];
    float c1 = xp[tid*12+1] + xp[tid*12+4] + xp[tid*12+7] + xp[tid*12+10];
    float c2 = xp[tid*12+2] + xp[tid*12+5] + xp[tid*12+8] + xp[tid*12+11];
    float s = 0.f, q = 0.f;
    #pragma unroll
    for (int e = 0; e < 3; e++){
      float v = nbl[e] + c0*nwl[e*3+0] + c1*nwl[e*3+1] + c2*nwl[e*3+2];
      X1[((size_t)b*R + tid)*3 + e] = v;
      s += v; q += v*v;
    }
    int sh = b & (NSH-1);
    atomicAdd(&xsumS[sh*STL + layer*R + tid], s);
    atomicAdd(&xsqS [sh*STL + layer*R + tid], q);
    atomicAdd(&zsumS[sh*STL + layer*R + tid], zps[tid*2] + zps[tid*2+1]);
    atomicAdd(&zsqS [sh*STL + layer*R + tid], zpq[tid*2] + zpq[tid*2+1]);
  }
}

// ---------------- apply BN (in place) to all XZ feature slots, t=0..4, one pass ----------------
__global__ void k_applyAll(const float* __restrict__ dnS, const float* __restrict__ deS,
                           const float* __restrict__ dng, const float* __restrict__ dnbe,
                           const float* __restrict__ deg, const float* __restrict__ debe,
                           ushort_t* __restrict__ XZ)
{
  int idx = blockIdx.x * 256 + threadIdx.x;    // BATCH*R
  int bi = idx / R, r = idx - bi*R;
  const float cn = (float)(BATCH * R);
  const float ce = (float)(BATCH * R * 3);
  #pragma unroll
  for (int t = 0; t < 5; t++){
    float mn = dnS[t*2+0] / cn;
    float vn = fmaxf(dnS[t*2+1] / cn - mn*mn, 0.f);
    size_t sn = (size_t)bi*XZS + t*R + r;
    float hn = (bf2f(XZ[sn]) - mn) * rsqrtf(vn + EPSF) * dng[t] + dnbe[t];
    XZ[sn] = f2bf(hn);
    float me = deS[t*2+0] / ce;
    float ve = fmaxf(deS[t*2+1] / ce - me*me, 0.f);
    float rse = rsqrtf(ve + EPSF);
    size_t se = (size_t)bi*XZS + 5*R + t*3*R + r*3;
    #pragma unroll
    for (int p = 0; p < 3; p++){
      float he = (bf2f(XZ[se+p]) - me) * rse * deg[t] + debe[t];
      XZ[se+p] = f2bf(he);
    }
  }
}

// ---------------- classifier: fc1 bf16 MFMA GEMM ----------------
__launch_bounds__(256)
__global__ void k_fc1(const ushort_t* __restrict__ XZ, const ushort_t* __restrict__ cw1p,
                      const float* __restrict__ cb1, float* __restrict__ H){
  const int tid  = threadIdx.x;
  const int lane = tid & 63;
  const int wave = tid >> 6;
  const int qm   = lane & 15;
  const int quad = lane >> 4;
  const int m0   = blockIdx.x * 64 + wave * 16;
  const int n0   = blockIdx.y * 64;

  const f32x4 vzero = {0.f, 0.f, 0.f, 0.f};
  f32x4 acc[4];
  #pragma unroll
  for (int t = 0; t < 4; t++) acc[t] = vzero;

  const ushort_t* arow = XZ + (size_t)(m0 + qm) * XZS;
  for (int kk = 0; kk < XZS; kk += 32){
    bf16x8 a = *(const bf16x8*)(arow + kk + quad*8);
    #pragma unroll
    for (int t = 0; t < 4; t++){
      const ushort_t* brow = cw1p + (size_t)(n0 + t*16 + qm) * XZS;
      bf16x8 bf = *(const bf16x8*)(brow + kk + quad*8);
      acc[t] = __builtin_amdgcn_mfma_f32_16x16x32_bf16(a, bf, acc[t], 0, 0, 0);
    }
  }
  #pragma unroll
  for (int t = 0; t < 4; t++){
    int n = n0 + t*16 + qm;
    float bias = cb1[n];
    #pragma unroll
    for (int rg = 0; rg < 4; rg++){
      int m = m0 + quad*4 + rg;
      H[(size_t)m * 1024 + n] = fmaxf(acc[t][rg] + bias, 0.f);
    }
  }
}

__global__ void k_fc2(const float* __restrict__ H, const float* __restrict__ cw2,
                      const float* __restrict__ cb2, float* __restrict__ out){
  int b = blockIdx.x, tid = threadIdx.x;
  float a0 = 0.f, a1 = 0.f;
  for (int j = tid; j < 1024; j += 256){
    float h = H[(size_t)b * 1024 + j];
    a0 += h * cw2[j];
    a1 += h * cw2[1024 + j];
  }
  a0 = wsum(a0); a1 = wsum(a1);
  __shared__ float s0[4], s1[4];
  int lane = tid & 63, wave = tid >> 6;
  if (lane == 0){ s0[wave] = a0; s1[wave] = a1; }
  __syncthreads();
  if (tid == 0){
    out[b*2 + 0] = s0[0]+s0[1]+s0[2]+s0[3] + cb2[0];
    out[b*2 + 1] = s1[0]+s1[1]+s1[2]+s1[3] + cb2[1];
  }
}

extern "C" void kernel_launch(void* const* d_in, const int* in_sizes, int n_in,
                              void* d_out, int out_size, void* d_ws, size_t ws_size,
                              hipStream_t stream)
{
  const float* Xin  = (const float*)d_in[0];
  const float* Zin  = (const float*)d_in[1];
  const float* aw1  = (const float*)d_in[2];
  const float* ab1  = (const float*)d_in[3];
  const float* aw2  = (const float*)d_in[4];
  const float* ab2  = (const float*)d_in[5];
  const float* nw   = (const float*)d_in[6];
  const float* nb   = (const float*)d_in[7];
  const float* ew   = (const float*)d_in[8];
  const float* eb   = (const float*)d_in[9];
  const float* gng  = (const float*)d_in[10];
  const float* gnb  = (const float*)d_in[11];
  const float* geg  = (const float*)d_in[12];
  const float* geb  = (const float*)d_in[13];
  const float* dnw  = (const float*)d_in[14];
  const float* dnb  = (const float*)d_in[15];
  const float* dng  = (const float*)d_in[16];
  const float* dnbe = (const float*)d_in[17];
  const float* dew  = (const float*)d_in[18];
  const float* deb  = (const float*)d_in[19];
  const float* deg  = (const float*)d_in[20];
  const float* debe = (const float*)d_in[21];
  const float* cw1  = (const float*)d_in[22];
  const float* cb1  = (const float*)d_in[23];
  const float* cw2  = (const float*)d_in[24];
  const float* cb2  = (const float*)d_in[25];

  // ---- workspace layout (unchanged) ----
  ushort_t* Zc = (ushort_t*)d_ws;            // bf16 Z state
  ushort_t* Z1 = Zc + NZ_ELEM;               // bf16 pre-BN Z1
  float*    H  = (float*)Z1;                 //   overlay: fc1 out (Z1 dead at fc1)
  float*    Xc = (float*)(Z1 + NZ_ELEM);     // fp32 X state
  float*    X1 = Xc + NX_ELEM;               // fp32 pre-BN X1
  ushort_t* XZ = (ushort_t*)(X1 + NX_ELEM);  // bf16 features (B,XZS)
  float*    st = (float*)(XZ + BATCH*XZS);   // stats: 14880 floats (sharded)
  ushort_t* aw2p = (ushort_t*)(st + 14880);
  ushort_t* ewp  = aw2p + 4*16384;
  ushort_t* cw1p = ewp + 4*16384;
  float* zsumS = st;               // [NSH][STL]
  float* zsqS  = st + 3712;
  float* xsumS = st + 7424;
  float* xsqS  = st + 11136;
  float* dnS   = st + 14848;       // [5][2]
  float* deS   = st + 14858;

  float* outp = (float*)d_out;

  // init (Z1 head zeroed: guard for k_fused's row-tail Z reads of graph 1023, layer 0)
  k_initZ<<<2048, 256, 0, stream>>>((const float4*)Zin, (uint4*)Zc, NZ_ELEM / 8);
  k_initX<<<1392, 256, 0, stream>>>(Xin, Xc, NX_ELEM, st, 14880,
                                    (unsigned*)XZ, BATCH*XZS/2, (unsigned*)Z1, 704);
  k_initW<<<256, 256, 0, stream>>>(aw2, ew, aw2p, ewp);
  k_initC<<<9344, 256, 0, stream>>>(cw1, cw1p);

  // fused layers (layer i prologue = BN/residual of layer i-1 + snapshot t=i; then attn i)
  for (int i = 0; i < NL; i++){
    k_fused<<<BATCH, 1024, 0, stream>>>(Xc, Zc, Z1, X1, aw1, ab1, aw2p, ab2,
                                        nw, nb, ewp, eb, zsumS, zsqS, xsumS, xsqS,
                                        geg, geb, gng, gnb, dnw, dnb, dew, deb,
                                        XZ, dnS, deS, i, 1);
  }
  // tail: BN/residual of layer 3 + snapshot t=4, no attention
  k_fused<<<BATCH, 1024, 0, stream>>>(Xc, Zc, Z1, X1, aw1, ab1, aw2p, ab2,
                                      nw, nb, ewp, eb, zsumS, zsqS, xsumS, xsqS,
                                      geg, geb, gng, gnb, dnw, dnb, dew, deb,
                                      XZ, dnS, deS, NL, 0);

  k_applyAll<<<464, 256, 0, stream>>>(dnS, deS, dng, dnbe, deg, debe, XZ);

  k_fc1<<<dim3(16, 16), 256, 0, stream>>>(XZ, cw1p, cb1, H);
  k_fc2<<<BATCH, 256, 0, stream>>>(H, cw2, cb2, outp);
}

// Round 3
// 741.852 us; speedup vs baseline: 1.6341x; 1.1676x over previous
//
#include <hip/hip_runtime.h>

#define R 116
#define BATCH 1024
#define NL 4
#define RR2 13456          // R*R
#define EPSF 1e-5f
#define NZ_ELEM (BATCH * RR2)     // 13,778,944
#define NX_ELEM (BATCH * R * 3)   //    356,352
#define LS 136                    // LDS row stride (bf16 elems)
#define XZS 2336                  // XZ/cw1p K-stride: 2320 padded to 73*32
#define NSH 8                     // stat shards (atomic contention divider)
#define STL 464                   // NL*R stats stride
#define NCH 1682                  // RR2/8 uint4 chunks per graph

typedef unsigned short ushort_t;
typedef __attribute__((ext_vector_type(8))) short bf16x8;
typedef __attribute__((ext_vector_type(4))) float f32x4;

__device__ __forceinline__ float bf2f(unsigned short u){
  union { unsigned int i; float f; } v; v.i = ((unsigned int)u) << 16; return v.f;
}
__device__ __forceinline__ unsigned short f2bf(float f){
  union { float ff; unsigned int i; } v; v.ff = f;
  return (unsigned short)((v.i + 0x7fffu + ((v.i >> 16) & 1u)) >> 16);
}
__device__ __forceinline__ float wsum(float v){
  #pragma unroll
  for (int o = 32; o > 0; o >>= 1) v += __shfl_xor(v, o, 64);
  return v;
}
__device__ __forceinline__ float wmaxr(float v){
  #pragma unroll
  for (int o = 32; o > 0; o >>= 1) v = fmaxf(v, __shfl_xor(v, o, 64));
  return v;
}
// 16B bf16 fragment load from an 8B-aligned global address (Z rows have 232B stride)
__device__ __forceinline__ bf16x8 ldg_z8(const ushort_t* p){
  union { uint2 u2[2]; bf16x8 v; } c;
  c.u2[0] = *(const uint2*)p;
  c.u2[1] = *(const uint2*)(p + 4);
  return c.v;
}

// ---------------- init: Z fp32 -> bf16 ----------------
__global__ void k_initZ(const float4* __restrict__ src, uint4* __restrict__ dst, int n8){
  int idx = blockIdx.x * blockDim.x + threadIdx.x;
  int stride = gridDim.x * blockDim.x;
  for (int i = idx; i < n8; i += stride){
    float4 a = src[2*i], b = src[2*i+1];
    uint4 w;
    w.x = (unsigned)f2bf(a.x) | ((unsigned)f2bf(a.y) << 16);
    w.y = (unsigned)f2bf(a.z) | ((unsigned)f2bf(a.w) << 16);
    w.z = (unsigned)f2bf(b.x) | ((unsigned)f2bf(b.y) << 16);
    w.w = (unsigned)f2bf(b.z) | ((unsigned)f2bf(b.w) << 16);
    dst[i] = w;
  }
}

// ---------------- init: copy X fp32, zero stats, zero XZ, zero Z1 OOB-read guard ----------------
__global__ void k_initX(const float* __restrict__ src, float* __restrict__ dst, int n,
                        float* __restrict__ stats, int nstats,
                        unsigned* __restrict__ xzw, int nxzw,
                        unsigned* __restrict__ z1g, int nz1g){
  int idx = blockIdx.x * blockDim.x + threadIdx.x;
  int stride = gridDim.x * blockDim.x;
  for (int i = idx; i < n; i += stride) dst[i] = src[i];
  for (int i = idx; i < nstats; i += stride) stats[i] = 0.f;
  for (int i = idx; i < nxzw; i += stride) xzw[i] = 0u;
  for (int i = idx; i < nz1g; i += stride) z1g[i] = 0u;  // guard: graph 1023 row-tail reads
}

// ---------------- init: pack aw2^T / ew for MFMA (128x128, bf16, zero-padded) ----------------
__global__ void k_initW(const float* __restrict__ aw2, const float* __restrict__ ew,
                        ushort_t* __restrict__ aw2p, ushort_t* __restrict__ ewp){
  int idx = blockIdx.x * 256 + threadIdx.x;   // 4*128*128
  int l = idx >> 14, rem = idx & 16383, row = rem >> 7, col = rem & 127;
  ushort_t v = 0, w = 0;
  if (row < R && col < R){
    v = f2bf(aw2[l*RR2 + col*R + row]);   // aw2p[row][col] = aw2[col][row]  (aw2^T)
    w = f2bf(ew [l*RR2 + row*R + col]);   // ewp [row][col] = ew[row][col]
  }
  aw2p[idx] = v;
  ewp [idx] = w;
}

// ---------------- init: pack cw1 -> bf16 [n][k], K padded to XZS ----------------
__global__ void k_initC(const float* __restrict__ cw1, ushort_t* __restrict__ cw1p){
  int idx = blockIdx.x * 256 + threadIdx.x;
  if (idx >= 1024 * XZS) return;
  int n = idx / XZS, k = idx - n * XZS;
  cw1p[idx] = (k < 2320) ? f2bf(cw1[n*2320 + k]) : (ushort_t)0;
}

// ==================================================================================
// Fused per-layer kernel.  Block b owns graph b.
//   Phase -1: per-row BN affine coeffs (a,c) -> LDS (aliased into xp); wsm.
//   P0: all 1024 threads stream Z via uint4 chunks: val = max(z1*a+c,0)+zc,
//       write Zc (layer>0) + stage linear copy in bB; threads 658-773 do X row
//       (BN+residual, Ksm, node downsample snapshot); others zero bA pads.
//   P1: waves 0-9 softmax -> bA(P); waves 10-15 edge downsample from bBlin.
//   Stages A,B',E,D unchanged (bB overwritten by W right after sync2).
//   layer==NL && !with_attn: prologue+downsamples only (snapshot t=4).
//   At layer 0 coeffs are 0 => val = zc exactly (NaN-safe vs garbage Z1).
// ==================================================================================
__launch_bounds__(1024, 8)
__global__ void k_fused(float* __restrict__ Xc, ushort_t* __restrict__ Zc,
                        ushort_t* __restrict__ Z1, float* __restrict__ X1,
                        const float* __restrict__ aw1, const float* __restrict__ ab1,
                        const ushort_t* __restrict__ aw2p, const float* __restrict__ ab2,
                        const float* __restrict__ nw,  const float* __restrict__ nb,
                        const ushort_t* __restrict__ ewp,  const float* __restrict__ eb,
                        float* __restrict__ zsumS, float* __restrict__ zsqS,
                        float* __restrict__ xsumS, float* __restrict__ xsqS,
                        const float* __restrict__ geg, const float* __restrict__ geb,
                        const float* __restrict__ gng, const float* __restrict__ gnb,
                        const float* __restrict__ dnw, const float* __restrict__ dnb,
                        const float* __restrict__ dew, const float* __restrict__ deb,
                        ushort_t* __restrict__ XZ,
                        float* __restrict__ dnS, float* __restrict__ deS,
                        int layer, int with_attn)
{
  __shared__ __align__(16) ushort_t bA[128*LS];    // P, then M (row-major)
  __shared__ __align__(16) ushort_t bB[128*LS];    // linear Z staging, then W, then E^T
  __shared__ float Ksm[3*R];
  __shared__ float ssm[R];
  __shared__ float xp[R*12];         // X-path partials; head aliased as BN coeffs in P0
  __shared__ float zps[128*2];       // per-row Z1 sum partials
  __shared__ float zpq[128*2];
  __shared__ float wsm[78];          // edge downsample weights
  __shared__ float xsred[3], xqred[3];
  __shared__ float zds[8], zqs[8];

  float* zcoA = xp;          // [R] BN coeff a for Z rows (dead before xp written)
  float* zcoC = xp + 116;
  float* xcoA = xp + 232;
  float* xcoC = xp + 348;
  ushort_t* bBlin = bB;      // linear staged Z view

  const int b    = blockIdx.x;
  const int tid  = threadIdx.x;
  const int lane = tid & 63;
  const int wave = tid >> 6;          // 16 waves
  const int qm   = lane & 15;
  const int quad = lane >> 4;
  const int tr   = wave & 7;
  const int tc0  = (wave >> 3) * 4;
  const int t_snap = layer;           // snapshot index for downsample outputs
  const int sh   = b & (NSH-1);

  ushort_t* Zb = Zc + (size_t)b * RR2;
  const ushort_t* Z1b = Z1 + (size_t)b * RR2;
  const float* ab2l = ab2 + layer * R;
  const float* ebl  = eb  + layer * R;
  const float* nwl  = nw  + layer * 9;
  const float* nbl  = nb  + layer * 3;
  const ushort_t* aw2l = aw2p + layer * 16384;
  const ushort_t* ewl  = ewp  + layer * 16384;

  const f32x4 vzero = {0.f, 0.f, 0.f, 0.f};

  // =============== Phase -1: per-row BN coeffs + wsm ===============
  if (tid < R){
    float a = 0.f, c = 0.f;
    if (layer > 0){
      const int pl = layer - 1;
      float ms = 0.f, qs = 0.f;
      #pragma unroll
      for (int s2 = 0; s2 < NSH; s2++){
        ms += zsumS[s2*STL + pl*R + tid];
        qs += zsqS [s2*STL + pl*R + tid];
      }
      const float cnt = (float)(BATCH * R);
      float m  = ms / cnt;
      float va = fmaxf(qs / cnt - m*m, 0.f);
      float rs = rsqrtf(va + EPSF);
      a = rs * geg[pl*R + tid];
      c = geb[pl*R + tid] - m * a;
    }
    zcoA[tid] = a; zcoC[tid] = c;
  } else if (tid >= 128 && tid < 128 + R){
    const int r = tid - 128;
    float a = 0.f, c = 0.f;
    if (layer > 0){
      const int pl = layer - 1;
      float ms = 0.f, qs = 0.f;
      #pragma unroll
      for (int s2 = 0; s2 < NSH; s2++){
        ms += xsumS[s2*STL + pl*R + r];
        qs += xsqS [s2*STL + pl*R + r];
      }
      const float cnt = (float)(BATCH * 3);
      float m  = ms / cnt;
      float va = fmaxf(qs / cnt - m*m, 0.f);
      float rs = rsqrtf(va + EPSF);
      a = rs * gng[pl*R + r];
      c = gnb[pl*R + r] - m * a;
    }
    xcoA[r] = a; xcoC[r] = c;
  } else if (tid >= 256 && tid < 256 + 78){
    wsm[tid - 256] = dew[t_snap*78 + (tid - 256)];
  }
  __syncthreads();   // ---- sync0 ----

  // =============== P0: full-width Z stream + X rows + bA pad zero ===============
  for (int ch = tid; ch < NCH; ch += 1024){
    const int e0 = ch << 3;
    const int r0 = e0 / 116;
    const int c0 = e0 - r0*116;
    uint4 zc4 = *(const uint4*)(Zb + e0);
    uint4 z14;
    if (layer > 0) z14 = *(const uint4*)(Z1b + e0);
    else { z14.x = 0u; z14.y = 0u; z14.z = 0u; z14.w = 0u; }
    unsigned zw[4]  = {zc4.x, zc4.y, zc4.z, zc4.w};
    unsigned z1w[4] = {z14.x, z14.y, z14.z, z14.w};
    unsigned ow[4];
    #pragma unroll
    for (int h = 0; h < 4; h++){
      int c1 = c0 + 2*h, c2 = c1 + 1;
      int rA = r0 + (c1 >= 116);
      int rB = r0 + (c2 >= 116);
      float aA = zcoA[rA], cA = zcoC[rA];
      float aB = zcoA[rB], cB = zcoC[rB];
      float zl  = bf2f((ushort_t)(zw[h] & 0xffffu));
      float zh  = bf2f((ushort_t)(zw[h] >> 16));
      float z1l = bf2f((ushort_t)(z1w[h] & 0xffffu));
      float z1h = bf2f((ushort_t)(z1w[h] >> 16));
      float vL = fmaxf(z1l*aA + cA, 0.f) + zl;
      float vH = fmaxf(z1h*aB + cB, 0.f) + zh;
      ow[h] = (unsigned)f2bf(vL) | ((unsigned)f2bf(vH) << 16);
    }
    uint4 o; o.x = ow[0]; o.y = ow[1]; o.z = ow[2]; o.w = ow[3];
    if (layer > 0) *(uint4*)(Zb + e0) = o;     // residual state write-back
    *(uint4*)&bBlin[e0] = o;                   // linear staging for downsample
  }
  // X rows on threads 658-773 (they had only 1 Z chunk)
  {
    float fv = 0.f;
    if (tid >= 658 && tid < 658 + R){
      const int u = tid - 658;
      float* xcr = Xc + ((size_t)b*R + u)*3;
      float a = xcoA[u], c = xcoC[u];
      float v0, v1, v2;
      if (layer > 0){
        const float* x1r = X1 + ((size_t)b*R + u)*3;
        v0 = fmaxf(x1r[0]*a + c, 0.f) + xcr[0];
        v1 = fmaxf(x1r[1]*a + c, 0.f) + xcr[1];
        v2 = fmaxf(x1r[2]*a + c, 0.f) + xcr[2];
        xcr[0] = v0; xcr[1] = v1; xcr[2] = v2;
      } else {
        v0 = xcr[0]; v1 = xcr[1]; v2 = xcr[2];
      }
      if (with_attn){
        const float* aw1l = aw1 + layer * 9;
        const float* ab1l = ab1 + layer * 3;
        #pragma unroll
        for (int o = 0; o < 3; o++)
          Ksm[o*R + u] = ab1l[o] + aw1l[o*3+0]*v0 + aw1l[o*3+1]*v1 + aw1l[o*3+2]*v2;
      }
      float f = fmaxf(dnw[t_snap*3+0]*v0 + dnw[t_snap*3+1]*v1 + dnw[t_snap*3+2]*v2 + dnb[t_snap], 0.f);
      XZ[(size_t)b*XZS + t_snap*R + u] = f2bf(f);
      fv = f;
    }
    if (wave >= 10 && wave <= 12){
      float s = wsum(fv), q = wsum(fv*fv);
      if (lane == 0){ xsred[wave - 10] = s; xqred[wave - 10] = q; }
    }
  }
  // bA pad zeroing (rows 116-127 full; cols 116-135 of rows <116) on threads 774+
  if (tid >= 774){
    for (int i = tid - 774; i < 12*LS; i += 250) bA[116*LS + i] = 0;
    for (int i = tid - 774; i < 116*20; i += 250){
      int r = i/20, c = 116 + (i - r*20);
      bA[r*LS + c] = 0;
    }
  }
  __syncthreads();   // ---- sync1 ----

  // =============== P1: softmax (waves 0-9) || edge downsample (waves 10-15) ===============
  if (wave < 10){
    if (tid == 0){
      atomicAdd(&dnS[sh*10 + t_snap*2+0], xsred[0] + xsred[1] + xsred[2]);
      atomicAdd(&dnS[sh*10 + t_snap*2+1], xqred[0] + xqred[1] + xqred[2]);
    }
    if (with_attn){
      for (int n = wave; n < R; n += 10){
        float k0 = Ksm[n], k1 = Ksm[R+n], k2 = Ksm[2*R+n];
        int m0 = lane, m1 = lane + 64;
        float a0 = k0*Ksm[m0] + k1*Ksm[R+m0] + k2*Ksm[2*R+m0];
        float a1 = (m1 < R) ? (k0*Ksm[m1] + k1*Ksm[R+m1] + k2*Ksm[2*R+m1]) : -1e30f;
        float mx = wmaxr(fmaxf(a0, a1));
        float e0 = __expf(a0 - mx);
        float e1 = (m1 < R) ? __expf(a1 - mx) : 0.f;
        float sm = wsum(e0 + e1);
        float sab = wsum(e0 * ab2l[m0] + ((m1 < R) ? e1 * ab2l[m1] : 0.f));
        float inv = 1.f / sm;
        bA[n*LS + m0] = f2bf(e0 * inv);
        if (m1 < R) bA[n*LS + m1] = f2bf(e1 * inv);
        if (lane == 0) ssm[n] = sab * inv;
      }
    }
  } else {
    const int u = tid - 640;          // 0..383; 348 active
    float f = 0.f;
    if (u < 348){
      int r = u / 3, w = u - 3*r;
      int jlo = (w == 0) ? 39 : 0;
      int jhi = (w == 2) ? 77 : 78;
      int off = (w - 1) * 39;
      const ushort_t* vr = &bBlin[r*116];
      float acc = 0.f;
      for (int j = jlo; j < jhi; j++) acc += wsm[j] * bf2f(vr[j + off]);
      f = fmaxf(acc + deb[t_snap], 0.f);
      XZ[(size_t)b*XZS + 5*R + t_snap*3*R + r*3 + w] = f2bf(f);
    }
    float s = wsum(f), q = wsum(f*f);
    if (lane == 0){ zds[wave - 10] = s; zqs[wave - 10] = q; }
  }
  __syncthreads();   // ---- sync2 ----

  if (tid == 0){
    float ss = 0.f, qq = 0.f;
    #pragma unroll
    for (int k = 0; k < 6; k++){ ss += zds[k]; qq += zqs[k]; }
    atomicAdd(&deS[sh*10 + t_snap*2+0], ss);
    atomicAdd(&deS[sh*10 + t_snap*2+1], qq);
  }
  if (!with_attn) return;

  // ---- Stage A: W^T-product = aw2^T @ P^T; transposed-packed write -> bB = W row-major ----
  {
    f32x4 acc[4];
    #pragma unroll
    for (int t = 0; t < 4; t++) acc[t] = vzero;
    for (int kk = 0; kk < 128; kk += 32){
      bf16x8 a = *(const bf16x8*)(aw2l + (tr*16 + qm)*128 + kk + quad*8);
      #pragma unroll
      for (int t = 0; t < 4; t++){
        bf16x8 bf = *(const bf16x8*)&bA[((tc0 + t)*16 + qm)*LS + kk + quad*8];
        acc[t] = __builtin_amdgcn_mfma_f32_16x16x32_bf16(a, bf, acc[t], 0, 0, 0);
      }
    }
    // sync2 already ordered P1's bBlin reads before these writes
    const int r0 = tr*16 + quad*4;
    #pragma unroll
    for (int t = 0; t < 4; t++){
      int nn = (tc0 + t)*16 + qm;
      uint2 w;
      w.x = (unsigned)f2bf(acc[t][0]) | ((unsigned)f2bf(acc[t][1]) << 16);
      w.y = (unsigned)f2bf(acc[t][2]) | ((unsigned)f2bf(acc[t][3]) << 16);
      *(uint2*)&bB[nn*LS + r0] = w;
    }
  }
  __syncthreads();

  // ---- Stage B': M^T = W @ Z^T (+ssm); Z fragments from global; transposed write -> bA = M ----
  {
    f32x4 acc[4];
    #pragma unroll
    for (int t = 0; t < 4; t++) acc[t] = vzero;
    for (int kk = 0; kk < 128; kk += 32){
      bf16x8 a = *(const bf16x8*)&bB[(tr*16 + qm)*LS + kk + quad*8];
      #pragma unroll
      for (int t = 0; t < 4; t++){
        int nn = (tc0 + t)*16 + qm;
        bf16x8 bf = ldg_z8(Zb + nn*R + kk + quad*8);
        acc[t] = __builtin_amdgcn_mfma_f32_16x16x32_bf16(a, bf, acc[t], 0, 0, 0);
      }
    }
    const int r0 = tr*16 + quad*4;
    float s0 = 0.f, s1 = 0.f, s2 = 0.f, s3 = 0.f;
    if (r0 < R){ s0 = ssm[r0]; s1 = ssm[r0+1]; s2 = ssm[r0+2]; s3 = ssm[r0+3]; }
    #pragma unroll
    for (int t = 0; t < 4; t++){
      int nn = (tc0 + t)*16 + qm;
      uint2 w;
      w.x = (unsigned)f2bf(acc[t][0] + s0) | ((unsigned)f2bf(acc[t][1] + s1) << 16);
      w.y = (unsigned)f2bf(acc[t][2] + s2) | ((unsigned)f2bf(acc[t][3] + s3) << 16);
      *(uint2*)&bA[nn*LS + r0] = w;
    }
  }
  __syncthreads();

  // ---- Stage E: E = Z @ ew^T; transposed write -> bB = E^T row-major (overwrites W) ----
  {
    f32x4 acc[4];
    #pragma unroll
    for (int t = 0; t < 4; t++) acc[t] = vzero;
    for (int kk = 0; kk < 128; kk += 32){
      bf16x8 a = ldg_z8(Zb + (tr*16 + qm)*R + kk + quad*8);
      #pragma unroll
      for (int t = 0; t < 4; t++){
        bf16x8 bf = *(const bf16x8*)(ewl + ((tc0 + t)*16 + qm)*128 + kk + quad*8);
        acc[t] = __builtin_amdgcn_mfma_f32_16x16x32_bf16(a, bf, acc[t], 0, 0, 0);
      }
    }
    const int r0 = tr*16 + quad*4;
    #pragma unroll
    for (int t = 0; t < 4; t++){
      int nn = (tc0 + t)*16 + qm;
      uint2 w;
      w.x = (unsigned)f2bf(acc[t][0]) | ((unsigned)f2bf(acc[t][1]) << 16);
      w.y = (unsigned)f2bf(acc[t][2]) | ((unsigned)f2bf(acc[t][3]) << 16);
      *(uint2*)&bB[nn*LS + r0] = w;
    }
  }
  __syncthreads();

  // ---- Stage D: Z1 = M @ E + eb -> global bf16; row stats -> LDS partials ----
  {
    f32x4 acc[4];
    #pragma unroll
    for (int t = 0; t < 4; t++) acc[t] = vzero;
    for (int kk = 0; kk < 128; kk += 32){
      bf16x8 a = *(const bf16x8*)&bA[(tr*16 + qm)*LS + kk + quad*8];
      #pragma unroll
      for (int t = 0; t < 4; t++){
        bf16x8 bf = *(const bf16x8*)&bB[((tc0 + t)*16 + qm)*LS + kk + quad*8];
        acc[t] = __builtin_amdgcn_mfma_f32_16x16x32_bf16(a, bf, acc[t], 0, 0, 0);
      }
    }
    float ssv[4] = {0.f,0.f,0.f,0.f}, sqv[4] = {0.f,0.f,0.f,0.f};
    #pragma unroll
    for (int t = 0; t < 4; t++){
      int col = (tc0 + t)*16 + qm;
      float bias = (col < R) ? ebl[col] : 0.f;
      #pragma unroll
      for (int rg = 0; rg < 4; rg++){
        int row = tr*16 + quad*4 + rg;
        float v = (col < R) ? (acc[t][rg] + bias) : 0.f;
        if (col < R && row < R)
          Z1[(size_t)b*RR2 + row*R + col] = f2bf(v);
        ssv[rg] += v; sqv[rg] += v*v;
      }
    }
    #pragma unroll
    for (int off = 1; off < 16; off <<= 1){
      #pragma unroll
      for (int rg = 0; rg < 4; rg++){
        ssv[rg] += __shfl_xor(ssv[rg], off, 64);
        sqv[rg] += __shfl_xor(sqv[rg], off, 64);
      }
    }
    if (qm == 0){
      int half = wave >> 3;
      #pragma unroll
      for (int rg = 0; rg < 4; rg++){
        int row = tr*16 + quad*4 + rg;
        zps[row*2 + half] = ssv[rg];
        zpq[row*2 + half] = sqv[rg];
      }
    }
  }

  // ---- X path partials: T1x = M @ X (M stable in bA) ----
  const float* Xb = Xc + (size_t)b * R * 3;
  if (tid < R*4){
    int n = tid >> 2, part = tid & 3;
    float t0 = 0.f, t1 = 0.f, t2 = 0.f;
    for (int m = part; m < R; m += 4){
      float p = bf2f(bA[n*LS + m]);
      const float* xr = Xb + m*3;
      t0 += p*xr[0]; t1 += p*xr[1]; t2 += p*xr[2];
    }
    xp[tid*3+0] = t0; xp[tid*3+1] = t1; xp[tid*3+2] = t2;
  }
  __syncthreads();
  if (tid < R){
    float c0 = xp[tid*12+0] + xp[tid*12+3] + xp[tid*12+6] + xp[tid*12+9];
    float c1 = xp[tid*12+1] + xp[tid*12+4] + xp[tid*12+7] + xp[tid*12+10];
    float c2 = xp[tid*12+2] + xp[tid*12+5] + xp[tid*12+8] + xp[tid*12+11];
    float s = 0.f, q = 0.f;
    #pragma unroll
    for (int e = 0; e < 3; e++){
      float v = nbl[e] + c0*nwl[e*3+0] + c1*nwl[e*3+1] + c2*nwl[e*3+2];
      X1[((size_t)b*R + tid)*3 + e] = v;
      s += v; q += v*v;
    }
    atomicAdd(&xsumS[sh*STL + layer*R + tid], s);
    atomicAdd(&xsqS [sh*STL + layer*R + tid], q);
    atomicAdd(&zsumS[sh*STL + layer*R + tid], zps[tid*2] + zps[tid*2+1]);
    atomicAdd(&zsqS [sh*STL + layer*R + tid], zpq[tid*2] + zpq[tid*2+1]);
  }
}

// ---------------- apply BN (in place) to all XZ feature slots, t=0..4, one pass ----------------
__global__ void k_applyAll(const float* __restrict__ dnS, const float* __restrict__ deS,
                           const float* __restrict__ dng, const float* __restrict__ dnbe,
                           const float* __restrict__ deg, const float* __restrict__ debe,
                           ushort_t* __restrict__ XZ)
{
  int idx = blockIdx.x * 256 + threadIdx.x;    // BATCH*R
  int bi = idx / R, r = idx - bi*R;
  const float cn = (float)(BATCH * R);
  const float ce = (float)(BATCH * R * 3);
  #pragma unroll
  for (int t = 0; t < 5; t++){
    float dns = 0.f, dnq = 0.f, des = 0.f, deq = 0.f;
    #pragma unroll
    for (int s2 = 0; s2 < NSH; s2++){
      dns += dnS[s2*10 + t*2+0]; dnq += dnS[s2*10 + t*2+1];
      des += deS[s2*10 + t*2+0]; deq += deS[s2*10 + t*2+1];
    }
    float mn = dns / cn;
    float vn = fmaxf(dnq / cn - mn*mn, 0.f);
    size_t sn = (size_t)bi*XZS + t*R + r;
    float hn = (bf2f(XZ[sn]) - mn) * rsqrtf(vn + EPSF) * dng[t] + dnbe[t];
    XZ[sn] = f2bf(hn);
    float me = des / ce;
    float ve = fmaxf(deq / ce - me*me, 0.f);
    float rse = rsqrtf(ve + EPSF);
    size_t se = (size_t)bi*XZS + 5*R + t*3*R + r*3;
    #pragma unroll
    for (int p = 0; p < 3; p++){
      float he = (bf2f(XZ[se+p]) - me) * rse * deg[t] + debe[t];
      XZ[se+p] = f2bf(he);
    }
  }
}

// ---------------- classifier: fc1 bf16 MFMA GEMM ----------------
__launch_bounds__(256)
__global__ void k_fc1(const ushort_t* __restrict__ XZ, const ushort_t* __restrict__ cw1p,
                      const float* __restrict__ cb1, float* __restrict__ H){
  const int tid  = threadIdx.x;
  const int lane = tid & 63;
  const int wave = tid >> 6;
  const int qm   = lane & 15;
  const int quad = lane >> 4;
  const int m0   = blockIdx.x * 64 + wave * 16;
  const int n0   = blockIdx.y * 64;

  const f32x4 vzero = {0.f, 0.f, 0.f, 0.f};
  f32x4 acc[4];
  #pragma unroll
  for (int t = 0; t < 4; t++) acc[t] = vzero;

  const ushort_t* arow = XZ + (size_t)(m0 + qm) * XZS;
  for (int kk = 0; kk < XZS; kk += 32){
    bf16x8 a = *(const bf16x8*)(arow + kk + quad*8);
    #pragma unroll
    for (int t = 0; t < 4; t++){
      const ushort_t* brow = cw1p + (size_t)(n0 + t*16 + qm) * XZS;
      bf16x8 bf = *(const bf16x8*)(brow + kk + quad*8);
      acc[t] = __builtin_amdgcn_mfma_f32_16x16x32_bf16(a, bf, acc[t], 0, 0, 0);
    }
  }
  #pragma unroll
  for (int t = 0; t < 4; t++){
    int n = n0 + t*16 + qm;
    float bias = cb1[n];
    #pragma unroll
    for (int rg = 0; rg < 4; rg++){
      int m = m0 + quad*4 + rg;
      H[(size_t)m * 1024 + n] = fmaxf(acc[t][rg] + bias, 0.f);
    }
  }
}

__global__ void k_fc2(const float* __restrict__ H, const float* __restrict__ cw2,
                      const float* __restrict__ cb2, float* __restrict__ out){
  int b = blockIdx.x, tid = threadIdx.x;
  float a0 = 0.f, a1 = 0.f;
  for (int j = tid; j < 1024; j += 256){
    float h = H[(size_t)b * 1024 + j];
    a0 += h * cw2[j];
    a1 += h * cw2[1024 + j];
  }
  a0 = wsum(a0); a1 = wsum(a1);
  __shared__ float s0[4], s1[4];
  int lane = tid & 63, wave = tid >> 6;
  if (lane == 0){ s0[wave] = a0; s1[wave] = a1; }
  __syncthreads();
  if (tid == 0){
    out[b*2 + 0] = s0[0]+s0[1]+s0[2]+s0[3] + cb2[0];
    out[b*2 + 1] = s1[0]+s1[1]+s1[2]+s1[3] + cb2[1];
  }
}

extern "C" void kernel_launch(void* const* d_in, const int* in_sizes, int n_in,
                              void* d_out, int out_size, void* d_ws, size_t ws_size,
                              hipStream_t stream)
{
  const float* Xin  = (const float*)d_in[0];
  const float* Zin  = (const float*)d_in[1];
  const float* aw1  = (const float*)d_in[2];
  const float* ab1  = (const float*)d_in[3];
  const float* aw2  = (const float*)d_in[4];
  const float* ab2  = (const float*)d_in[5];
  const float* nw   = (const float*)d_in[6];
  const float* nb   = (const float*)d_in[7];
  const float* ew   = (const float*)d_in[8];
  const float* eb   = (const float*)d_in[9];
  const float* gng  = (const float*)d_in[10];
  const float* gnb  = (const float*)d_in[11];
  const float* geg  = (const float*)d_in[12];
  const float* geb  = (const float*)d_in[13];
  const float* dnw  = (const float*)d_in[14];
  const float* dnb  = (const float*)d_in[15];
  const float* dng  = (const float*)d_in[16];
  const float* dnbe = (const float*)d_in[17];
  const float* dew  = (const float*)d_in[18];
  const float* deb  = (const float*)d_in[19];
  const float* deg  = (const float*)d_in[20];
  const float* debe = (const float*)d_in[21];
  const float* cw1  = (const float*)d_in[22];
  const float* cb1  = (const float*)d_in[23];
  const float* cw2  = (const float*)d_in[24];
  const float* cb2  = (const float*)d_in[25];

  // ---- workspace layout (stats area grown by 128 floats for sharded dnS/deS) ----
  ushort_t* Zc = (ushort_t*)d_ws;            // bf16 Z state
  ushort_t* Z1 = Zc + NZ_ELEM;               // bf16 pre-BN Z1
  float*    H  = (float*)Z1;                 //   overlay: fc1 out (Z1 dead at fc1)
  float*    Xc = (float*)(Z1 + NZ_ELEM);     // fp32 X state
  float*    X1 = Xc + NX_ELEM;               // fp32 pre-BN X1
  ushort_t* XZ = (ushort_t*)(X1 + NX_ELEM);  // bf16 features (B,XZS)
  float*    st = (float*)(XZ + BATCH*XZS);   // stats: 15008 floats (sharded)
  float* zsumS = st;               // [NSH][STL]
  float* zsqS  = st + 3712;
  float* xsumS = st + 7424;
  float* xsqS  = st + 11136;
  float* dnS   = st + 14848;       // [NSH][10]
  float* deS   = st + 14928;       // [NSH][10]
  ushort_t* aw2p = (ushort_t*)(st + 15008);
  ushort_t* ewp  = aw2p + 4*16384;
  ushort_t* cw1p = ewp + 4*16384;

  float* outp = (float*)d_out;

  // init (Z1 head zeroed: guard for k_fused's row-tail Z reads of graph 1023, layer 0)
  k_initZ<<<2048, 256, 0, stream>>>((const float4*)Zin, (uint4*)Zc, NZ_ELEM / 8);
  k_initX<<<1392, 256, 0, stream>>>(Xin, Xc, NX_ELEM, st, 15008,
                                    (unsigned*)XZ, BATCH*XZS/2, (unsigned*)Z1, 704);
  k_initW<<<256, 256, 0, stream>>>(aw2, ew, aw2p, ewp);
  k_initC<<<9344, 256, 0, stream>>>(cw1, cw1p);

  // fused layers (layer i prologue = BN/residual of layer i-1 + snapshot t=i; then attn i)
  for (int i = 0; i < NL; i++){
    k_fused<<<BATCH, 1024, 0, stream>>>(Xc, Zc, Z1, X1, aw1, ab1, aw2p, ab2,
                                        nw, nb, ewp, eb, zsumS, zsqS, xsumS, xsqS,
                                        geg, geb, gng, gnb, dnw, dnb, dew, deb,
                                        XZ, dnS, deS, i, 1);
  }
  // tail: BN/residual of layer 3 + snapshot t=4, no attention
  k_fused<<<BATCH, 1024, 0, stream>>>(Xc, Zc, Z1, X1, aw1, ab1, aw2p, ab2,
                                      nw, nb, ewp, eb, zsumS, zsqS, xsumS, xsqS,
                                      geg, geb, gng, gnb, dnw, dnb, dew, deb,
                                      XZ, dnS, deS, NL, 0);

  k_applyAll<<<464, 256, 0, stream>>>(dnS, deS, dng, dnbe, deg, debe, XZ);

  k_fc1<<<dim3(16, 16), 256, 0, stream>>>(XZ, cw1p, cb1, H);
  k_fc2<<<BATCH, 256, 0, stream>>>(H, cw2, cb2, outp);
}

// Round 6
// 671.438 us; speedup vs baseline: 1.8055x; 1.1049x over previous
//
#include <hip/hip_runtime.h>

#define R 116
#define BATCH 1024
#define NL 4
#define RR2 13456          // R*R
#define EPSF 1e-5f
#define NZ_ELEM (BATCH * RR2)     // 13,778,944
#define NX_ELEM (BATCH * R * 3)   //    356,352
#define LS 136                    // LDS row stride (bf16 elems)
#define XZS 2336                  // XZ/cw1p K-stride: 2320 padded to 73*32
#define NSH 8                     // stat shards (atomic contention divider)
#define STL 464                   // NL*R stats stride
#define NCH 1682                  // RR2/8 uint4 chunks per graph

typedef unsigned short ushort_t;
typedef __attribute__((ext_vector_type(8))) short bf16x8;
typedef __attribute__((ext_vector_type(4))) float f32x4;

__device__ __forceinline__ float bf2f(unsigned short u){
  union { unsigned int i; float f; } v; v.i = ((unsigned int)u) << 16; return v.f;
}
__device__ __forceinline__ unsigned short f2bf(float f){
  union { float ff; unsigned int i; } v; v.ff = f;
  return (unsigned short)((v.i + 0x7fffu + ((v.i >> 16) & 1u)) >> 16);
}
__device__ __forceinline__ float wsum(float v){
  #pragma unroll
  for (int o = 32; o > 0; o >>= 1) v += __shfl_xor(v, o, 64);
  return v;
}
__device__ __forceinline__ float wmaxr(float v){
  #pragma unroll
  for (int o = 32; o > 0; o >>= 1) v = fmaxf(v, __shfl_xor(v, o, 64));
  return v;
}
// 16B bf16 fragment load from an 8B-aligned global address (Z rows have 232B stride)
__device__ __forceinline__ bf16x8 ldg_z8(const ushort_t* p){
  union { uint2 u2[2]; bf16x8 v; } c;
  c.u2[0] = *(const uint2*)p;
  c.u2[1] = *(const uint2*)(p + 4);
  return c.v;
}

// ---------------- merged init: Z conv, cw1/aw2/ew pack, X copy, zeroing, out=cb2 ----------------
__global__ void k_init(const float4* __restrict__ Zin, uint4* __restrict__ Zc8,
                       const float* __restrict__ Xin, float* __restrict__ Xc,
                       float* __restrict__ st, unsigned* __restrict__ xzw,
                       unsigned* __restrict__ z1g,
                       const float* __restrict__ aw2, const float* __restrict__ ew,
                       ushort_t* __restrict__ aw2p, ushort_t* __restrict__ ewp,
                       const float* __restrict__ cw1, ushort_t* __restrict__ cw1p,
                       const float* __restrict__ cb2, float* __restrict__ out)
{
  int idx = blockIdx.x * 256 + threadIdx.x;
  int stride = gridDim.x * 256;
  for (int i = idx; i < NZ_ELEM/8; i += stride){
    float4 a = Zin[2*i], b = Zin[2*i+1];
    uint4 w;
    w.x = (unsigned)f2bf(a.x) | ((unsigned)f2bf(a.y) << 16);
    w.y = (unsigned)f2bf(a.z) | ((unsigned)f2bf(a.w) << 16);
    w.z = (unsigned)f2bf(b.x) | ((unsigned)f2bf(b.y) << 16);
    w.w = (unsigned)f2bf(b.z) | ((unsigned)f2bf(b.w) << 16);
    Zc8[i] = w;
  }
  for (int i = idx; i < 1024 * XZS; i += stride){
    int n = i / XZS, k = i - n * XZS;
    cw1p[i] = (k < 2320) ? f2bf(cw1[n*2320 + k]) : (ushort_t)0;
  }
  for (int i = idx; i < 4*128*128; i += stride){
    int l = i >> 14, rem = i & 16383, row = rem >> 7, col = rem & 127;
    ushort_t v = 0, w = 0;
    if (row < R && col < R){
      v = f2bf(aw2[l*RR2 + col*R + row]);   // aw2p[row][col] = aw2[col][row]  (aw2^T)
      w = f2bf(ew [l*RR2 + row*R + col]);   // ewp [row][col] = ew[row][col]
    }
    aw2p[i] = v;
    ewp [i] = w;
  }
  for (int i = idx; i < NX_ELEM; i += stride) Xc[i] = Xin[i];
  for (int i = idx; i < 15008; i += stride) st[i] = 0.f;
  for (int i = idx; i < BATCH*XZS/2; i += stride) xzw[i] = 0u;
  for (int i = idx; i < 704; i += stride) z1g[i] = 0u;   // guard: graph 1023 row-tail reads
  for (int i = idx; i < 1024; i += stride){ out[2*i] = cb2[0]; out[2*i+1] = cb2[1]; }
}

// ==================================================================================
// Fused per-layer kernel (byte-identical to the verified 741us version).
//   Phase -1: per-row BN affine coeffs -> LDS (aliased into xp); wsm.
//   P0: all 1024 threads stream Z via uint4 chunks: val = max(z1*a+c,0)+zc,
//       write Zc (layer>0) + stage linear copy in bB; threads 658-773 do X row
//       (BN+residual, Ksm, node downsample snapshot); threads 774+ zero bA pads.
//   P1: waves 0-9 softmax -> bA(P); waves 10-15 edge downsample from bBlin.
//   Stages A,B',E,D: MFMA pipeline (Z1 = M@(Z@ew^T)); X-path scalar reads of M.
// ==================================================================================
__launch_bounds__(1024, 8)
__global__ void k_fused(float* __restrict__ Xc, ushort_t* __restrict__ Zc,
                        ushort_t* __restrict__ Z1, float* __restrict__ X1,
                        const float* __restrict__ aw1, const float* __restrict__ ab1,
                        const ushort_t* __restrict__ aw2p, const float* __restrict__ ab2,
                        const float* __restrict__ nw,  const float* __restrict__ nb,
                        const ushort_t* __restrict__ ewp,  const float* __restrict__ eb,
                        float* __restrict__ zsumS, float* __restrict__ zsqS,
                        float* __restrict__ xsumS, float* __restrict__ xsqS,
                        const float* __restrict__ geg, const float* __restrict__ geb,
                        const float* __restrict__ gng, const float* __restrict__ gnb,
                        const float* __restrict__ dnw, const float* __restrict__ dnb,
                        const float* __restrict__ dew, const float* __restrict__ deb,
                        ushort_t* __restrict__ XZ,
                        float* __restrict__ dnS, float* __restrict__ deS,
                        int layer, int with_attn)
{
  __shared__ __align__(16) ushort_t bA[128*LS];    // P, then M (row-major)
  __shared__ __align__(16) ushort_t bB[128*LS];    // linear Z staging, then W, then E^T
  __shared__ float Ksm[3*R];
  __shared__ float ssm[R];
  __shared__ float xp[R*12];         // X-path partials; head aliased as BN coeffs in P0
  __shared__ float zps[128*2];       // per-row Z1 sum partials
  __shared__ float zpq[128*2];
  __shared__ float wsm[78];          // edge downsample weights
  __shared__ float xsred[3], xqred[3];
  __shared__ float zds[8], zqs[8];

  float* zcoA = xp;          // [R] BN coeff a for Z rows (dead before xp written)
  float* zcoC = xp + 116;
  float* xcoA = xp + 232;
  float* xcoC = xp + 348;
  ushort_t* bBlin = bB;      // linear staged Z view

  const int b    = blockIdx.x;
  const int tid  = threadIdx.x;
  const int lane = tid & 63;
  const int wave = tid >> 6;          // 16 waves
  const int qm   = lane & 15;
  const int quad = lane >> 4;
  const int tr   = wave & 7;
  const int tc0  = (wave >> 3) * 4;
  const int t_snap = layer;           // snapshot index for downsample outputs
  const int sh   = b & (NSH-1);

  ushort_t* Zb = Zc + (size_t)b * RR2;
  const ushort_t* Z1b = Z1 + (size_t)b * RR2;
  const float* ab2l = ab2 + layer * R;
  const float* ebl  = eb  + layer * R;
  const float* nwl  = nw  + layer * 9;
  const float* nbl  = nb  + layer * 3;
  const ushort_t* aw2l = aw2p + layer * 16384;
  const ushort_t* ewl  = ewp  + layer * 16384;

  const f32x4 vzero = {0.f, 0.f, 0.f, 0.f};

  // =============== Phase -1: per-row BN coeffs + wsm ===============
  if (tid < R){
    float a = 0.f, c = 0.f;
    if (layer > 0){
      const int pl = layer - 1;
      float ms = 0.f, qs = 0.f;
      #pragma unroll
      for (int s2 = 0; s2 < NSH; s2++){
        ms += zsumS[s2*STL + pl*R + tid];
        qs += zsqS [s2*STL + pl*R + tid];
      }
      const float cnt = (float)(BATCH * R);
      float m  = ms / cnt;
      float va = fmaxf(qs / cnt - m*m, 0.f);
      float rs = rsqrtf(va + EPSF);
      a = rs * geg[pl*R + tid];
      c = geb[pl*R + tid] - m * a;
    }
    zcoA[tid] = a; zcoC[tid] = c;
  } else if (tid >= 128 && tid < 128 + R){
    const int r = tid - 128;
    float a = 0.f, c = 0.f;
    if (layer > 0){
      const int pl = layer - 1;
      float ms = 0.f, qs = 0.f;
      #pragma unroll
      for (int s2 = 0; s2 < NSH; s2++){
        ms += xsumS[s2*STL + pl*R + r];
        qs += xsqS [s2*STL + pl*R + r];
      }
      const float cnt = (float)(BATCH * 3);
      float m  = ms / cnt;
      float va = fmaxf(qs / cnt - m*m, 0.f);
      float rs = rsqrtf(va + EPSF);
      a = rs * gng[pl*R + r];
      c = gnb[pl*R + r] - m * a;
    }
    xcoA[r] = a; xcoC[r] = c;
  } else if (tid >= 256 && tid < 256 + 78){
    wsm[tid - 256] = dew[t_snap*78 + (tid - 256)];
  }
  __syncthreads();   // ---- sync0 ----

  // =============== P0: full-width Z stream + X rows + bA pad zero ===============
  for (int ch = tid; ch < NCH; ch += 1024){
    const int e0 = ch << 3;
    const int r0 = e0 / 116;
    const int c0 = e0 - r0*116;
    uint4 zc4 = *(const uint4*)(Zb + e0);
    uint4 z14;
    if (layer > 0) z14 = *(const uint4*)(Z1b + e0);
    else { z14.x = 0u; z14.y = 0u; z14.z = 0u; z14.w = 0u; }
    unsigned zw[4]  = {zc4.x, zc4.y, zc4.z, zc4.w};
    unsigned z1w[4] = {z14.x, z14.y, z14.z, z14.w};
    unsigned ow[4];
    #pragma unroll
    for (int h = 0; h < 4; h++){
      int c1 = c0 + 2*h, c2 = c1 + 1;
      int rA = r0 + (c1 >= 116);
      int rB = r0 + (c2 >= 116);
      float aA = zcoA[rA], cA = zcoC[rA];
      float aB = zcoA[rB], cB = zcoC[rB];
      float zl  = bf2f((ushort_t)(zw[h] & 0xffffu));
      float zh  = bf2f((ushort_t)(zw[h] >> 16));
      float z1l = bf2f((ushort_t)(z1w[h] & 0xffffu));
      float z1h = bf2f((ushort_t)(z1w[h] >> 16));
      float vL = fmaxf(z1l*aA + cA, 0.f) + zl;
      float vH = fmaxf(z1h*aB + cB, 0.f) + zh;
      ow[h] = (unsigned)f2bf(vL) | ((unsigned)f2bf(vH) << 16);
    }
    uint4 o; o.x = ow[0]; o.y = ow[1]; o.z = ow[2]; o.w = ow[3];
    if (layer > 0) *(uint4*)(Zb + e0) = o;     // residual state write-back
    *(uint4*)&bBlin[e0] = o;                   // linear staging for downsample
  }
  // X rows on threads 658-773 (they had only 1 Z chunk)
  {
    float fv = 0.f;
    if (tid >= 658 && tid < 658 + R){
      const int u = tid - 658;
      float* xcr = Xc + ((size_t)b*R + u)*3;
      float v0, v1, v2;
      if (layer > 0){
        float a = xcoA[u], c = xcoC[u];
        const float* x1r = X1 + ((size_t)b*R + u)*3;
        v0 = fmaxf(x1r[0]*a + c, 0.f) + xcr[0];
        v1 = fmaxf(x1r[1]*a + c, 0.f) + xcr[1];
        v2 = fmaxf(x1r[2]*a + c, 0.f) + xcr[2];
        xcr[0] = v0; xcr[1] = v1; xcr[2] = v2;
      } else {
        v0 = xcr[0]; v1 = xcr[1]; v2 = xcr[2];
      }
      if (with_attn){
        const float* aw1l = aw1 + layer * 9;
        const float* ab1l = ab1 + layer * 3;
        #pragma unroll
        for (int o = 0; o < 3; o++)
          Ksm[o*R + u] = ab1l[o] + aw1l[o*3+0]*v0 + aw1l[o*3+1]*v1 + aw1l[o*3+2]*v2;
      }
      float f = fmaxf(dnw[t_snap*3+0]*v0 + dnw[t_snap*3+1]*v1 + dnw[t_snap*3+2]*v2 + dnb[t_snap], 0.f);
      XZ[(size_t)b*XZS + t_snap*R + u] = f2bf(f);
      fv = f;
    }
    if (wave >= 10 && wave <= 12){
      float s = wsum(fv), q = wsum(fv*fv);
      if (lane == 0){ xsred[wave - 10] = s; xqred[wave - 10] = q; }
    }
  }
  // bA pad zeroing (rows 116-127 full; cols 116-135 of rows <116) on threads 774+
  if (tid >= 774){
    for (int i = tid - 774; i < 12*LS; i += 250) bA[116*LS + i] = 0;
    for (int i = tid - 774; i < 116*20; i += 250){
      int r = i/20, c = 116 + (i - r*20);
      bA[r*LS + c] = 0;
    }
  }
  __syncthreads();   // ---- sync1 ----

  // =============== P1: softmax (waves 0-9) || edge downsample (waves 10-15) ===============
  if (wave < 10){
    if (tid == 0){
      atomicAdd(&dnS[sh*10 + t_snap*2+0], xsred[0] + xsred[1] + xsred[2]);
      atomicAdd(&dnS[sh*10 + t_snap*2+1], xqred[0] + xqred[1] + xqred[2]);
    }
    if (with_attn){
      for (int n = wave; n < R; n += 10){
        float k0 = Ksm[n], k1 = Ksm[R+n], k2 = Ksm[2*R+n];
        int m0 = lane, m1 = lane + 64;
        float a0 = k0*Ksm[m0] + k1*Ksm[R+m0] + k2*Ksm[2*R+m0];
        float a1 = (m1 < R) ? (k0*Ksm[m1] + k1*Ksm[R+m1] + k2*Ksm[2*R+m1]) : -1e30f;
        float mx = wmaxr(fmaxf(a0, a1));
        float e0 = __expf(a0 - mx);
        float e1 = (m1 < R) ? __expf(a1 - mx) : 0.f;
        float sm = wsum(e0 + e1);
        float sab = wsum(e0 * ab2l[m0] + ((m1 < R) ? e1 * ab2l[m1] : 0.f));
        float inv = 1.f / sm;
        bA[n*LS + m0] = f2bf(e0 * inv);
        if (m1 < R) bA[n*LS + m1] = f2bf(e1 * inv);
        if (lane == 0) ssm[n] = sab * inv;
      }
    }
  } else {
    const int u = tid - 640;          // 0..383; 348 active
    float f = 0.f;
    if (u < 348){
      int r = u / 3, w = u - 3*r;
      int jlo = (w == 0) ? 39 : 0;
      int jhi = (w == 2) ? 77 : 78;
      int off = (w - 1) * 39;
      const ushort_t* vr = &bBlin[r*116];
      float acc = 0.f;
      for (int j = jlo; j < jhi; j++) acc += wsm[j] * bf2f(vr[j + off]);
      f = fmaxf(acc + deb[t_snap], 0.f);
      XZ[(size_t)b*XZS + 5*R + t_snap*3*R + r*3 + w] = f2bf(f);
    }
    float s = wsum(f), q = wsum(f*f);
    if (lane == 0){ zds[wave - 10] = s; zqs[wave - 10] = q; }
  }
  __syncthreads();   // ---- sync2 ----

  if (tid == 0){
    float ss = 0.f, qq = 0.f;
    #pragma unroll
    for (int k = 0; k < 6; k++){ ss += zds[k]; qq += zqs[k]; }
    atomicAdd(&deS[sh*10 + t_snap*2+0], ss);
    atomicAdd(&deS[sh*10 + t_snap*2+1], qq);
  }
  if (!with_attn) return;

  // ---- Stage A: W^T-product = aw2^T @ P^T; transposed-packed write -> bB = W row-major ----
  {
    f32x4 acc[4];
    #pragma unroll
    for (int t = 0; t < 4; t++) acc[t] = vzero;
    for (int kk = 0; kk < 128; kk += 32){
      bf16x8 a = *(const bf16x8*)(aw2l + (tr*16 + qm)*128 + kk + quad*8);
      #pragma unroll
      for (int t = 0; t < 4; t++){
        bf16x8 bf = *(const bf16x8*)&bA[((tc0 + t)*16 + qm)*LS + kk + quad*8];
        acc[t] = __builtin_amdgcn_mfma_f32_16x16x32_bf16(a, bf, acc[t], 0, 0, 0);
      }
    }
    // sync2 already ordered P1's bBlin reads before these writes
    const int r0 = tr*16 + quad*4;
    #pragma unroll
    for (int t = 0; t < 4; t++){
      int nn = (tc0 + t)*16 + qm;
      uint2 w;
      w.x = (unsigned)f2bf(acc[t][0]) | ((unsigned)f2bf(acc[t][1]) << 16);
      w.y = (unsigned)f2bf(acc[t][2]) | ((unsigned)f2bf(acc[t][3]) << 16);
      *(uint2*)&bB[nn*LS + r0] = w;
    }
  }
  __syncthreads();

  // ---- Stage B': M^T = W @ Z^T (+ssm); Z fragments from global; transposed write -> bA = M ----
  {
    f32x4 acc[4];
    #pragma unroll
    for (int t = 0; t < 4; t++) acc[t] = vzero;
    for (int kk = 0; kk < 128; kk += 32){
      bf16x8 a = *(const bf16x8*)&bB[(tr*16 + qm)*LS + kk + quad*8];
      #pragma unroll
      for (int t = 0; t < 4; t++){
        int nn = (tc0 + t)*16 + qm;
        bf16x8 bf = ldg_z8(Zb + nn*R + kk + quad*8);
        acc[t] = __builtin_amdgcn_mfma_f32_16x16x32_bf16(a, bf, acc[t], 0, 0, 0);
      }
    }
    const int r0 = tr*16 + quad*4;
    float s0 = 0.f, s1 = 0.f, s2 = 0.f, s3 = 0.f;
    if (r0 < R){ s0 = ssm[r0]; s1 = ssm[r0+1]; s2 = ssm[r0+2]; s3 = ssm[r0+3]; }
    #pragma unroll
    for (int t = 0; t < 4; t++){
      int nn = (tc0 + t)*16 + qm;
      uint2 w;
      w.x = (unsigned)f2bf(acc[t][0] + s0) | ((unsigned)f2bf(acc[t][1] + s1) << 16);
      w.y = (unsigned)f2bf(acc[t][2] + s2) | ((unsigned)f2bf(acc[t][3] + s3) << 16);
      *(uint2*)&bA[nn*LS + r0] = w;
    }
  }
  __syncthreads();

  // ---- Stage E: E = Z @ ew^T; transposed write -> bB = E^T row-major (overwrites W) ----
  {
    f32x4 acc[4];
    #pragma unroll
    for (int t = 0; t < 4; t++) acc[t] = vzero;
    for (int kk = 0; kk < 128; kk += 32){
      bf16x8 a = ldg_z8(Zb + (tr*16 + qm)*R + kk + quad*8);
      #pragma unroll
      for (int t = 0; t < 4; t++){
        bf16x8 bf = *(const bf16x8*)(ewl + ((tc0 + t)*16 + qm)*128 + kk + quad*8);
        acc[t] = __builtin_amdgcn_mfma_f32_16x16x32_bf16(a, bf, acc[t], 0, 0, 0);
      }
    }
    const int r0 = tr*16 + quad*4;
    #pragma unroll
    for (int t = 0; t < 4; t++){
      int nn = (tc0 + t)*16 + qm;
      uint2 w;
      w.x = (unsigned)f2bf(acc[t][0]) | ((unsigned)f2bf(acc[t][1]) << 16);
      w.y = (unsigned)f2bf(acc[t][2]) | ((unsigned)f2bf(acc[t][3]) << 16);
      *(uint2*)&bB[nn*LS + r0] = w;
    }
  }
  __syncthreads();

  // ---- Stage D: Z1 = M @ E + eb -> global bf16; row stats -> LDS partials ----
  {
    f32x4 acc[4];
    #pragma unroll
    for (int t = 0; t < 4; t++) acc[t] = vzero;
    for (int kk = 0; kk < 128; kk += 32){
      bf16x8 a = *(const bf16x8*)&bA[(tr*16 + qm)*LS + kk + quad*8];
      #pragma unroll
      for (int t = 0; t < 4; t++){
        bf16x8 bf = *(const bf16x8*)&bB[((tc0 + t)*16 + qm)*LS + kk + quad*8];
        acc[t] = __builtin_amdgcn_mfma_f32_16x16x32_bf16(a, bf, acc[t], 0, 0, 0);
      }
    }
    float ssv[4] = {0.f,0.f,0.f,0.f}, sqv[4] = {0.f,0.f,0.f,0.f};
    #pragma unroll
    for (int t = 0; t < 4; t++){
      int col = (tc0 + t)*16 + qm;
      float bias = (col < R) ? ebl[col] : 0.f;
      #pragma unroll
      for (int rg = 0; rg < 4; rg++){
        int row = tr*16 + quad*4 + rg;
        float v = (col < R) ? (acc[t][rg] + bias) : 0.f;
        if (col < R && row < R)
          Z1[(size_t)b*RR2 + row*R + col] = f2bf(v);
        ssv[rg] += v; sqv[rg] += v*v;
      }
    }
    #pragma unroll
    for (int off = 1; off < 16; off <<= 1){
      #pragma unroll
      for (int rg = 0; rg < 4; rg++){
        ssv[rg] += __shfl_xor(ssv[rg], off, 64);
        sqv[rg] += __shfl_xor(sqv[rg], off, 64);
      }
    }
    if (qm == 0){
      int half = wave >> 3;
      #pragma unroll
      for (int rg = 0; rg < 4; rg++){
        int row = tr*16 + quad*4 + rg;
        zps[row*2 + half] = ssv[rg];
        zpq[row*2 + half] = sqv[rg];
      }
    }
  }

  // ---- X path partials: T1x = M @ X (M stable in bA) ----
  const float* Xb = Xc + (size_t)b * R * 3;
  if (tid < R*4){
    int n = tid >> 2, part = tid & 3;
    float t0 = 0.f, t1 = 0.f, t2 = 0.f;
    for (int m = part; m < R; m += 4){
      float p = bf2f(bA[n*LS + m]);
      const float* xr = Xb + m*3;
      t0 += p*xr[0]; t1 += p*xr[1]; t2 += p*xr[2];
    }
    xp[tid*3+0] = t0; xp[tid*3+1] = t1; xp[tid*3+2] = t2;
  }
  __syncthreads();
  if (tid < R){
    float c0 = xp[tid*12+0] + xp[tid*12+3] + xp[tid*12+6] + xp[tid*12+9];
    float c1 = xp[tid*12+1] + xp[tid*12+4] + xp[tid*12+7] + xp[tid*12+10];
    float c2 = xp[tid*12+2] + xp[tid*12+5] + xp[tid*12+8] + xp[tid*12+11];
    float s = 0.f, q = 0.f;
    #pragma unroll
    for (int e = 0; e < 3; e++){
      float v = nbl[e] + c0*nwl[e*3+0] + c1*nwl[e*3+1] + c2*nwl[e*3+2];
      X1[((size_t)b*R + tid)*3 + e] = v;
      s += v; q += v*v;
    }
    atomicAdd(&xsumS[sh*STL + layer*R + tid], s);
    atomicAdd(&xsqS [sh*STL + layer*R + tid], q);
    atomicAdd(&zsumS[sh*STL + layer*R + tid], zps[tid*2] + zps[tid*2+1]);
    atomicAdd(&zsqS [sh*STL + layer*R + tid], zpq[tid*2] + zpq[tid*2+1]);
  }
}

// ---------------- apply BN (in place) to all XZ feature slots, t=0..4, one pass ----------------
__global__ void k_applyAll(const float* __restrict__ dnS, const float* __restrict__ deS,
                           const float* __restrict__ dng, const float* __restrict__ dnbe,
                           const float* __restrict__ deg, const float* __restrict__ debe,
                           ushort_t* __restrict__ XZ)
{
  int idx = blockIdx.x * 256 + threadIdx.x;    // BATCH*R
  int bi = idx / R, r = idx - bi*R;
  const float cn = (float)(BATCH * R);
  const float ce = (float)(BATCH * R * 3);
  #pragma unroll
  for (int t = 0; t < 5; t++){
    float dns = 0.f, dnq = 0.f, des = 0.f, deq = 0.f;
    #pragma unroll
    for (int s2 = 0; s2 < NSH; s2++){
      dns += dnS[s2*10 + t*2+0]; dnq += dnS[s2*10 + t*2+1];
      des += deS[s2*10 + t*2+0]; deq += deS[s2*10 + t*2+1];
    }
    float mn = dns / cn;
    float vn = fmaxf(dnq / cn - mn*mn, 0.f);
    size_t sn = (size_t)bi*XZS + t*R + r;
    float hn = (bf2f(XZ[sn]) - mn) * rsqrtf(vn + EPSF) * dng[t] + dnbe[t];
    XZ[sn] = f2bf(hn);
    float me = des / ce;
    float ve = fmaxf(deq / ce - me*me, 0.f);
    float rse = rsqrtf(ve + EPSF);
    size_t se = (size_t)bi*XZS + 5*R + t*3*R + r*3;
    #pragma unroll
    for (int p = 0; p < 3; p++){
      float he = (bf2f(XZ[se+p]) - me) * rse * deg[t] + debe[t];
      XZ[se+p] = f2bf(he);
    }
  }
}

// ---------------- classifier: fc1 MFMA GEMM with fused fc2 reduction ----------------
__launch_bounds__(256)
__global__ void k_fc(const ushort_t* __restrict__ XZ, const ushort_t* __restrict__ cw1p,
                     const float* __restrict__ cb1, const float* __restrict__ cw2,
                     float* __restrict__ out){
  const int tid  = threadIdx.x;
  const int lane = tid & 63;
  const int wave = tid >> 6;
  const int qm   = lane & 15;
  const int quad = lane >> 4;
  const int m0   = blockIdx.x * 64 + wave * 16;
  const int n0   = blockIdx.y * 64;

  const f32x4 vzero = {0.f, 0.f, 0.f, 0.f};
  f32x4 acc[4];
  #pragma unroll
  for (int t = 0; t < 4; t++) acc[t] = vzero;

  const ushort_t* arow = XZ + (size_t)(m0 + qm) * XZS;
  for (int kk = 0; kk < XZS; kk += 32){
    bf16x8 a = *(const bf16x8*)(arow + kk + quad*8);
    #pragma unroll
    for (int t = 0; t < 4; t++){
      const ushort_t* brow = cw1p + (size_t)(n0 + t*16 + qm) * XZS;
      bf16x8 bf = *(const bf16x8*)(brow + kk + quad*8);
      acc[t] = __builtin_amdgcn_mfma_f32_16x16x32_bf16(a, bf, acc[t], 0, 0, 0);
    }
  }
  // fused fc2: h = relu(acc + cb1); partial dot with cw2 rows; qm-reduce; atomic out
  #pragma unroll
  for (int rg = 0; rg < 4; rg++){
    float p0 = 0.f, p1 = 0.f;
    #pragma unroll
    for (int t = 0; t < 4; t++){
      int n = n0 + t*16 + qm;
      float h = fmaxf(acc[t][rg] + cb1[n], 0.f);
      p0 = fmaf(h, cw2[n], p0);
      p1 = fmaf(h, cw2[1024 + n], p1);
    }
    #pragma unroll
    for (int o = 1; o < 16; o <<= 1){
      p0 += __shfl_xor(p0, o, 64);
      p1 += __shfl_xor(p1, o, 64);
    }
    if (qm == 0){
      int m = m0 + quad*4 + rg;
      atomicAdd(&out[m*2 + 0], p0);
      atomicAdd(&out[m*2 + 1], p1);
    }
  }
}

extern "C" void kernel_launch(void* const* d_in, const int* in_sizes, int n_in,
                              void* d_out, int out_size, void* d_ws, size_t ws_size,
                              hipStream_t stream)
{
  const float* Xin  = (const float*)d_in[0];
  const float* Zin  = (const float*)d_in[1];
  const float* aw1  = (const float*)d_in[2];
  const float* ab1  = (const float*)d_in[3];
  const float* aw2  = (const float*)d_in[4];
  const float* ab2  = (const float*)d_in[5];
  const float* nw   = (const float*)d_in[6];
  const float* nb   = (const float*)d_in[7];
  const float* ew   = (const float*)d_in[8];
  const float* eb   = (const float*)d_in[9];
  const float* gng  = (const float*)d_in[10];
  const float* gnb  = (const float*)d_in[11];
  const float* geg  = (const float*)d_in[12];
  const float* geb  = (const float*)d_in[13];
  const float* dnw  = (const float*)d_in[14];
  const float* dnb  = (const float*)d_in[15];
  const float* dng  = (const float*)d_in[16];
  const float* dnbe = (const float*)d_in[17];
  const float* dew  = (const float*)d_in[18];
  const float* deb  = (const float*)d_in[19];
  const float* deg  = (const float*)d_in[20];
  const float* debe = (const float*)d_in[21];
  const float* cw1  = (const float*)d_in[22];
  const float* cb1  = (const float*)d_in[23];
  const float* cw2  = (const float*)d_in[24];
  const float* cb2  = (const float*)d_in[25];

  // ---- workspace layout (total 67,857,024 B < 69,605,444 B proven addressable) ----
  ushort_t* Zc = (ushort_t*)d_ws;            // bf16 Z state
  ushort_t* Z1 = Zc + NZ_ELEM;               // bf16 pre-BN Z1
  float*    Xc = (float*)(Z1 + NZ_ELEM);     // fp32 X state
  float*    X1 = Xc + NX_ELEM;               // fp32 pre-BN X1
  ushort_t* XZ = (ushort_t*)(X1 + NX_ELEM);  // bf16 features (B,XZS)
  float*    st = (float*)(XZ + BATCH*XZS);   // stats: 15008 floats (sharded)
  float* zsumS = st;               // [NSH][STL]
  float* zsqS  = st + 3712;
  float* xsumS = st + 7424;
  float* xsqS  = st + 11136;
  float* dnS   = st + 14848;       // [NSH][10]
  float* deS   = st + 14928;       // [NSH][10]
  ushort_t* aw2p = (ushort_t*)(st + 15008);
  ushort_t* ewp  = aw2p + 4*16384;
  ushort_t* cw1p = ewp + 4*16384;

  float* outp = (float*)d_out;

  // merged init (also seeds out = cb2 for the fused-fc atomic accumulation)
  k_init<<<4096, 256, 0, stream>>>((const float4*)Zin, (uint4*)Zc, Xin, Xc,
                                   st, (unsigned*)XZ, (unsigned*)Z1,
                                   aw2, ew, aw2p, ewp, cw1, cw1p, cb2, outp);

  // fused layers (layer i prologue = BN/residual of layer i-1 + snapshot t=i; then attn i)
  for (int i = 0; i < NL; i++){
    k_fused<<<BATCH, 1024, 0, stream>>>(Xc, Zc, Z1, X1, aw1, ab1, aw2p, ab2,
                                        nw, nb, ewp, eb, zsumS, zsqS, xsumS, xsqS,
                                        geg, geb, gng, gnb, dnw, dnb, dew, deb,
                                        XZ, dnS, deS, i, 1);
  }
  // tail: BN/residual of layer 3 + snapshot t=4, no attention
  k_fused<<<BATCH, 1024, 0, stream>>>(Xc, Zc, Z1, X1, aw1, ab1, aw2p, ab2,
                                      nw, nb, ewp, eb, zsumS, zsqS, xsumS, xsqS,
                                      geg, geb, gng, gnb, dnw, dnb, dew, deb,
                                      XZ, dnS, deS, NL, 0);

  k_applyAll<<<464, 256, 0, stream>>>(dnS, deS, dng, dnbe, deg, debe, XZ);

  k_fc<<<dim3(16, 16), 256, 0, stream>>>(XZ, cw1p, cb1, cw2, outp);
}

// Round 9
// 653.126 us; speedup vs baseline: 1.8561x; 1.0280x over previous
//
#include <hip/hip_runtime.h>

#define R 116
#define BATCH 1024
#define NL 4
#define RR2 13456          // R*R
#define EPSF 1e-5f
#define NZ_ELEM (BATCH * RR2)     // 13,778,944
#define NX_ELEM (BATCH * R * 3)   //    356,352
#define LS 136                    // LDS row stride (bf16 elems)
#define XZS 2336                  // XZ/cw1p K-stride: 2320 padded to 73*32
#define NSH 8                     // stat shards (atomic contention divider)
#define STL 464                   // NL*R stats stride
#define NCH 1682                  // RR2/8 uint4 chunks per graph

typedef unsigned short ushort_t;
typedef __attribute__((ext_vector_type(8))) short bf16x8;
typedef __attribute__((ext_vector_type(4))) float f32x4;

__device__ __forceinline__ float bf2f(unsigned short u){
  union { unsigned int i; float f; } v; v.i = ((unsigned int)u) << 16; return v.f;
}
__device__ __forceinline__ unsigned short f2bf(float f){
  union { float ff; unsigned int i; } v; v.ff = f;
  return (unsigned short)((v.i + 0x7fffu + ((v.i >> 16) & 1u)) >> 16);
}
// NOTE: hand-written v_cvt_pk_bf16_f32 asm is QUARANTINED — rounds 5/8 failed with
// identical absmax 1.41 whenever it was present (suspected operand-order/rounding
// mismatch vs the documented recipe). All conversions use the proven f2bf.
// bf16 pair unpack from one dword: 1 VALU op each
__device__ __forceinline__ float u2f_lo(unsigned w){
  union { unsigned i; float f; } v; v.i = w << 16; return v.f;
}
__device__ __forceinline__ float u2f_hi(unsigned w){
  union { unsigned i; float f; } v; v.i = w & 0xffff0000u; return v.f;
}
__device__ __forceinline__ float wsum(float v){
  #pragma unroll
  for (int o = 32; o > 0; o >>= 1) v += __shfl_xor(v, o, 64);
  return v;
}
__device__ __forceinline__ float wmaxr(float v){
  #pragma unroll
  for (int o = 32; o > 0; o >>= 1) v = fmaxf(v, __shfl_xor(v, o, 64));
  return v;
}
// 16B bf16 fragment load from an 8B-aligned global address (Z rows have 232B stride)
__device__ __forceinline__ bf16x8 ldg_z8(const ushort_t* p){
  union { uint2 u2[2]; bf16x8 v; } c;
  c.u2[0] = *(const uint2*)p;
  c.u2[1] = *(const uint2*)(p + 4);
  return c.v;
}

// ---------------- merged init: Z conv, cw1/aw2/ew pack, X copy, zeroing, out=cb2 ----------------
// (byte-identical to the round-6 passing version)
__global__ void k_init(const float4* __restrict__ Zin, uint4* __restrict__ Zc8,
                       const float* __restrict__ Xin, float* __restrict__ Xc,
                       float* __restrict__ st, unsigned* __restrict__ xzw,
                       unsigned* __restrict__ z1g,
                       const float* __restrict__ aw2, const float* __restrict__ ew,
                       ushort_t* __restrict__ aw2p, ushort_t* __restrict__ ewp,
                       const float* __restrict__ cw1, ushort_t* __restrict__ cw1p,
                       const float* __restrict__ cb2, float* __restrict__ out)
{
  int idx = blockIdx.x * 256 + threadIdx.x;
  int stride = gridDim.x * 256;
  for (int i = idx; i < NZ_ELEM/8; i += stride){
    float4 a = Zin[2*i], b = Zin[2*i+1];
    uint4 w;
    w.x = (unsigned)f2bf(a.x) | ((unsigned)f2bf(a.y) << 16);
    w.y = (unsigned)f2bf(a.z) | ((unsigned)f2bf(a.w) << 16);
    w.z = (unsigned)f2bf(b.x) | ((unsigned)f2bf(b.y) << 16);
    w.w = (unsigned)f2bf(b.z) | ((unsigned)f2bf(b.w) << 16);
    Zc8[i] = w;
  }
  for (int i = idx; i < 1024 * XZS; i += stride){
    int n = i / XZS, k = i - n * XZS;
    cw1p[i] = (k < 2320) ? f2bf(cw1[n*2320 + k]) : (ushort_t)0;
  }
  for (int i = idx; i < 4*128*128; i += stride){
    int l = i >> 14, rem = i & 16383, row = rem >> 7, col = rem & 127;
    ushort_t v = 0, w = 0;
    if (row < R && col < R){
      v = f2bf(aw2[l*RR2 + col*R + row]);   // aw2p[row][col] = aw2[col][row]  (aw2^T)
      w = f2bf(ew [l*RR2 + row*R + col]);   // ewp [row][col] = ew[row][col]
    }
    aw2p[i] = v;
    ewp [i] = w;
  }
  for (int i = idx; i < NX_ELEM; i += stride) Xc[i] = Xin[i];
  for (int i = idx; i < 15008; i += stride) st[i] = 0.f;
  for (int i = idx; i < BATCH*XZS/2; i += stride) xzw[i] = 0u;
  for (int i = idx; i < 704; i += stride) z1g[i] = 0u;   // guard: graph 1023 row-tail reads
  for (int i = idx; i < 1024; i += stride){ out[2*i] = cb2[0]; out[2*i+1] = cb2[1]; }
}

// ==================================================================================
// Fused per-layer kernel.  Round-6 passing base + ONLY two provable restructurings:
//   (a) P0 chunk-level BN coeff hoist (c0 always %4==0; row crossing only at c0==112,
//       clean half split) + 1-op bf16 unpacks;
//   (b) X-path vectorized uint2 LDS reads (partition {4p+16k..4p+3+16k} covers
//       m in [0,116) exactly once; 8B-aligned since LS=136, mb%4==0).
// All bf16 conversions remain the proven f2bf; stage-D stores remain scalar.
// ==================================================================================
__launch_bounds__(1024, 8)
__global__ void k_fused(float* __restrict__ Xc, ushort_t* __restrict__ Zc,
                        ushort_t* __restrict__ Z1, float* __restrict__ X1,
                        const float* __restrict__ aw1, const float* __restrict__ ab1,
                        const ushort_t* __restrict__ aw2p, const float* __restrict__ ab2,
                        const float* __restrict__ nw,  const float* __restrict__ nb,
                        const ushort_t* __restrict__ ewp,  const float* __restrict__ eb,
                        float* __restrict__ zsumS, float* __restrict__ zsqS,
                        float* __restrict__ xsumS, float* __restrict__ xsqS,
                        const float* __restrict__ geg, const float* __restrict__ geb,
                        const float* __restrict__ gng, const float* __restrict__ gnb,
                        const float* __restrict__ dnw, const float* __restrict__ dnb,
                        const float* __restrict__ dew, const float* __restrict__ deb,
                        ushort_t* __restrict__ XZ,
                        float* __restrict__ dnS, float* __restrict__ deS,
                        int layer, int with_attn)
{
  __shared__ __align__(16) ushort_t bA[128*LS];    // P, then M (row-major)
  __shared__ __align__(16) ushort_t bB[128*LS];    // linear Z staging, then W, then E^T
  __shared__ float Ksm[3*R];
  __shared__ float ssm[R];
  __shared__ float xp[R*12];         // X-path partials; head aliased as BN coeffs in P0
  __shared__ float zps[128*2];       // per-row Z1 sum partials
  __shared__ float zpq[128*2];
  __shared__ float wsm[78];          // edge downsample weights
  __shared__ float xsred[3], xqred[3];
  __shared__ float zds[8], zqs[8];

  float* zcoA = xp;          // [R] BN coeff a for Z rows (dead before xp written)
  float* zcoC = xp + 116;
  float* xcoA = xp + 232;
  float* xcoC = xp + 348;
  ushort_t* bBlin = bB;      // linear staged Z view

  const int b    = blockIdx.x;
  const int tid  = threadIdx.x;
  const int lane = tid & 63;
  const int wave = tid >> 6;          // 16 waves
  const int qm   = lane & 15;
  const int quad = lane >> 4;
  const int tr   = wave & 7;
  const int tc0  = (wave >> 3) * 4;
  const int t_snap = layer;           // snapshot index for downsample outputs
  const int sh   = b & (NSH-1);

  ushort_t* Zb = Zc + (size_t)b * RR2;
  const ushort_t* Z1b = Z1 + (size_t)b * RR2;
  const float* ab2l = ab2 + layer * R;
  const float* ebl  = eb  + layer * R;
  const float* nwl  = nw  + layer * 9;
  const float* nbl  = nb  + layer * 3;
  const ushort_t* aw2l = aw2p + layer * 16384;
  const ushort_t* ewl  = ewp  + layer * 16384;

  const f32x4 vzero = {0.f, 0.f, 0.f, 0.f};

  // =============== Phase -1: per-row BN coeffs + wsm ===============
  if (tid < R){
    float a = 0.f, c = 0.f;
    if (layer > 0){
      const int pl = layer - 1;
      float ms = 0.f, qs = 0.f;
      #pragma unroll
      for (int s2 = 0; s2 < NSH; s2++){
        ms += zsumS[s2*STL + pl*R + tid];
        qs += zsqS [s2*STL + pl*R + tid];
      }
      const float cnt = (float)(BATCH * R);
      float m  = ms / cnt;
      float va = fmaxf(qs / cnt - m*m, 0.f);
      float rs = rsqrtf(va + EPSF);
      a = rs * geg[pl*R + tid];
      c = geb[pl*R + tid] - m * a;
    }
    zcoA[tid] = a; zcoC[tid] = c;
  } else if (tid >= 128 && tid < 128 + R){
    const int r = tid - 128;
    float a = 0.f, c = 0.f;
    if (layer > 0){
      const int pl = layer - 1;
      float ms = 0.f, qs = 0.f;
      #pragma unroll
      for (int s2 = 0; s2 < NSH; s2++){
        ms += xsumS[s2*STL + pl*R + r];
        qs += xsqS [s2*STL + pl*R + r];
      }
      const float cnt = (float)(BATCH * 3);
      float m  = ms / cnt;
      float va = fmaxf(qs / cnt - m*m, 0.f);
      float rs = rsqrtf(va + EPSF);
      a = rs * gng[pl*R + r];
      c = gnb[pl*R + r] - m * a;
    }
    xcoA[r] = a; xcoC[r] = c;
  } else if (tid >= 256 && tid < 256 + 78){
    wsm[tid - 256] = dew[t_snap*78 + (tid - 256)];
  }
  __syncthreads();   // ---- sync0 ----

  // =============== P0: full-width Z stream + X rows + bA pad zero ===============
  for (int ch = tid; ch < NCH; ch += 1024){
    const int e0 = ch << 3;
    const int r0 = e0 / 116;
    const int c0 = e0 - r0*116;      // multiple of 4; crosses row only at c0==112 (clean half split)
    uint4 zc4 = *(const uint4*)(Zb + e0);
    if (layer > 0){
      uint4 z14 = *(const uint4*)(Z1b + e0);
      float aA = zcoA[r0], cA = zcoC[r0];
      float aB = aA, cB = cA;
      if (c0 == 112){ aB = zcoA[r0+1]; cB = zcoC[r0+1]; }
      const unsigned zw[4]  = {zc4.x, zc4.y, zc4.z, zc4.w};
      const unsigned z1w[4] = {z14.x, z14.y, z14.z, z14.w};
      unsigned ow[4];
      #pragma unroll
      for (int h = 0; h < 4; h++){
        float aa = (h < 2) ? aA : aB;
        float cc = (h < 2) ? cA : cB;
        float vL = fmaxf(u2f_lo(z1w[h])*aa + cc, 0.f) + u2f_lo(zw[h]);
        float vH = fmaxf(u2f_hi(z1w[h])*aa + cc, 0.f) + u2f_hi(zw[h]);
        ow[h] = (unsigned)f2bf(vL) | ((unsigned)f2bf(vH) << 16);
      }
      uint4 o; o.x = ow[0]; o.y = ow[1]; o.z = ow[2]; o.w = ow[3];
      *(uint4*)(Zb + e0) = o;                  // residual state write-back
      *(uint4*)&bBlin[e0] = o;                 // linear staging for downsample
    } else {
      *(uint4*)&bBlin[e0] = zc4;               // raw Z for t=0 snapshot (bit-identical)
    }
  }
  // X rows on threads 658-773 (they had only 1 Z chunk)
  {
    float fv = 0.f;
    if (tid >= 658 && tid < 658 + R){
      const int u = tid - 658;
      float* xcr = Xc + ((size_t)b*R + u)*3;
      float v0, v1, v2;
      if (layer > 0){
        float a = xcoA[u], c = xcoC[u];
        const float* x1r = X1 + ((size_t)b*R + u)*3;
        v0 = fmaxf(x1r[0]*a + c, 0.f) + xcr[0];
        v1 = fmaxf(x1r[1]*a + c, 0.f) + xcr[1];
        v2 = fmaxf(x1r[2]*a + c, 0.f) + xcr[2];
        xcr[0] = v0; xcr[1] = v1; xcr[2] = v2;
      } else {
        v0 = xcr[0]; v1 = xcr[1]; v2 = xcr[2];
      }
      if (with_attn){
        const float* aw1l = aw1 + layer * 9;
        const float* ab1l = ab1 + layer * 3;
        #pragma unroll
        for (int o = 0; o < 3; o++)
          Ksm[o*R + u] = ab1l[o] + aw1l[o*3+0]*v0 + aw1l[o*3+1]*v1 + aw1l[o*3+2]*v2;
      }
      float f = fmaxf(dnw[t_snap*3+0]*v0 + dnw[t_snap*3+1]*v1 + dnw[t_snap*3+2]*v2 + dnb[t_snap], 0.f);
      XZ[(size_t)b*XZS + t_snap*R + u] = f2bf(f);
      fv = f;
    }
    if (wave >= 10 && wave <= 12){
      float s = wsum(fv), q = wsum(fv*fv);
      if (lane == 0){ xsred[wave - 10] = s; xqred[wave - 10] = q; }
    }
  }
  // bA pad zeroing (rows 116-127 full; cols 116-135 of rows <116) on threads 774+
  if (tid >= 774){
    for (int i = tid - 774; i < 12*LS; i += 250) bA[116*LS + i] = 0;
    for (int i = tid - 774; i < 116*20; i += 250){
      int r = i/20, c = 116 + (i - r*20);
      bA[r*LS + c] = 0;
    }
  }
  __syncthreads();   // ---- sync1 ----

  // =============== P1: softmax (waves 0-9) || edge downsample (waves 10-15) ===============
  if (wave < 10){
    if (tid == 0){
      atomicAdd(&dnS[sh*10 + t_snap*2+0], xsred[0] + xsred[1] + xsred[2]);
      atomicAdd(&dnS[sh*10 + t_snap*2+1], xqred[0] + xqred[1] + xqred[2]);
    }
    if (with_attn){
      for (int n = wave; n < R; n += 10){
        float k0 = Ksm[n], k1 = Ksm[R+n], k2 = Ksm[2*R+n];
        int m0 = lane, m1 = lane + 64;
        float a0 = k0*Ksm[m0] + k1*Ksm[R+m0] + k2*Ksm[2*R+m0];
        float a1 = (m1 < R) ? (k0*Ksm[m1] + k1*Ksm[R+m1] + k2*Ksm[2*R+m1]) : -1e30f;
        float mx = wmaxr(fmaxf(a0, a1));
        float e0 = __expf(a0 - mx);
        float e1 = (m1 < R) ? __expf(a1 - mx) : 0.f;
        float sm = wsum(e0 + e1);
        float sab = wsum(e0 * ab2l[m0] + ((m1 < R) ? e1 * ab2l[m1] : 0.f));
        float inv = 1.f / sm;
        bA[n*LS + m0] = f2bf(e0 * inv);
        if (m1 < R) bA[n*LS + m1] = f2bf(e1 * inv);
        if (lane == 0) ssm[n] = sab * inv;
      }
    }
  } else {
    const int u = tid - 640;          // 0..383; 348 active
    float f = 0.f;
    if (u < 348){
      int r = u / 3, w = u - 3*r;
      int jlo = (w == 0) ? 39 : 0;
      int jhi = (w == 2) ? 77 : 78;
      int off = (w - 1) * 39;
      const ushort_t* vr = &bBlin[r*116];
      float acc = 0.f;
      for (int j = jlo; j < jhi; j++) acc += wsm[j] * bf2f(vr[j + off]);
      f = fmaxf(acc + deb[t_snap], 0.f);
      XZ[(size_t)b*XZS + 5*R + t_snap*3*R + r*3 + w] = f2bf(f);
    }
    float s = wsum(f), q = wsum(f*f);
    if (lane == 0){ zds[wave - 10] = s; zqs[wave - 10] = q; }
  }
  __syncthreads();   // ---- sync2 ----

  if (tid == 0){
    float ss = 0.f, qq = 0.f;
    #pragma unroll
    for (int k = 0; k < 6; k++){ ss += zds[k]; qq += zqs[k]; }
    atomicAdd(&deS[sh*10 + t_snap*2+0], ss);
    atomicAdd(&deS[sh*10 + t_snap*2+1], qq);
  }
  if (!with_attn) return;

  // ---- Stage A: W^T-product = aw2^T @ P^T; transposed-packed write -> bB = W row-major ----
  {
    f32x4 acc[4];
    #pragma unroll
    for (int t = 0; t < 4; t++) acc[t] = vzero;
    for (int kk = 0; kk < 128; kk += 32){
      bf16x8 a = *(const bf16x8*)(aw2l + (tr*16 + qm)*128 + kk + quad*8);
      #pragma unroll
      for (int t = 0; t < 4; t++){
        bf16x8 bf = *(const bf16x8*)&bA[((tc0 + t)*16 + qm)*LS + kk + quad*8];
        acc[t] = __builtin_amdgcn_mfma_f32_16x16x32_bf16(a, bf, acc[t], 0, 0, 0);
      }
    }
    // sync2 already ordered P1's bBlin reads before these writes
    const int r0 = tr*16 + quad*4;
    #pragma unroll
    for (int t = 0; t < 4; t++){
      int nn = (tc0 + t)*16 + qm;
      uint2 w;
      w.x = (unsigned)f2bf(acc[t][0]) | ((unsigned)f2bf(acc[t][1]) << 16);
      w.y = (unsigned)f2bf(acc[t][2]) | ((unsigned)f2bf(acc[t][3]) << 16);
      *(uint2*)&bB[nn*LS + r0] = w;
    }
  }
  __syncthreads();

  // ---- Stage B': M^T = W @ Z^T (+ssm); Z fragments from global; transposed write -> bA = M ----
  {
    f32x4 acc[4];
    #pragma unroll
    for (int t = 0; t < 4; t++) acc[t] = vzero;
    for (int kk = 0; kk < 128; kk += 32){
      bf16x8 a = *(const bf16x8*)&bB[(tr*16 + qm)*LS + kk + quad*8];
      #pragma unroll
      for (int t = 0; t < 4; t++){
        int nn = (tc0 + t)*16 + qm;
        bf16x8 bf = ldg_z8(Zb + nn*R + kk + quad*8);
        acc[t] = __builtin_amdgcn_mfma_f32_16x16x32_bf16(a, bf, acc[t], 0, 0, 0);
      }
    }
    const int r0 = tr*16 + quad*4;
    float s0 = 0.f, s1 = 0.f, s2 = 0.f, s3 = 0.f;
    if (r0 < R){ s0 = ssm[r0]; s1 = ssm[r0+1]; s2 = ssm[r0+2]; s3 = ssm[r0+3]; }
    #pragma unroll
    for (int t = 0; t < 4; t++){
      int nn = (tc0 + t)*16 + qm;
      uint2 w;
      w.x = (unsigned)f2bf(acc[t][0] + s0) | ((unsigned)f2bf(acc[t][1] + s1) << 16);
      w.y = (unsigned)f2bf(acc[t][2] + s2) | ((unsigned)f2bf(acc[t][3] + s3) << 16);
      *(uint2*)&bA[nn*LS + r0] = w;
    }
  }
  __syncthreads();

  // ---- Stage E: E = Z @ ew^T; transposed write -> bB = E^T row-major (overwrites W) ----
  {
    f32x4 acc[4];
    #pragma unroll
    for (int t = 0; t < 4; t++) acc[t] = vzero;
    for (int kk = 0; kk < 128; kk += 32){
      bf16x8 a = ldg_z8(Zb + (tr*16 + qm)*R + kk + quad*8);
      #pragma unroll
      for (int t = 0; t < 4; t++){
        bf16x8 bf = *(const bf16x8*)(ewl + ((tc0 + t)*16 + qm)*128 + kk + quad*8);
        acc[t] = __builtin_amdgcn_mfma_f32_16x16x32_bf16(a, bf, acc[t], 0, 0, 0);
      }
    }
    const int r0 = tr*16 + quad*4;
    #pragma unroll
    for (int t = 0; t < 4; t++){
      int nn = (tc0 + t)*16 + qm;
      uint2 w;
      w.x = (unsigned)f2bf(acc[t][0]) | ((unsigned)f2bf(acc[t][1]) << 16);
      w.y = (unsigned)f2bf(acc[t][2]) | ((unsigned)f2bf(acc[t][3]) << 16);
      *(uint2*)&bB[nn*LS + r0] = w;
    }
  }
  __syncthreads();

  // ---- Stage D: Z1 = M @ E + eb -> global bf16; row stats -> LDS partials ----
  {
    f32x4 acc[4];
    #pragma unroll
    for (int t = 0; t < 4; t++) acc[t] = vzero;
    for (int kk = 0; kk < 128; kk += 32){
      bf16x8 a = *(const bf16x8*)&bA[(tr*16 + qm)*LS + kk + quad*8];
      #pragma unroll
      for (int t = 0; t < 4; t++){
        bf16x8 bf = *(const bf16x8*)&bB[((tc0 + t)*16 + qm)*LS + kk + quad*8];
        acc[t] = __builtin_amdgcn_mfma_f32_16x16x32_bf16(a, bf, acc[t], 0, 0, 0);
      }
    }
    float ssv[4] = {0.f,0.f,0.f,0.f}, sqv[4] = {0.f,0.f,0.f,0.f};
    #pragma unroll
    for (int t = 0; t < 4; t++){
      int col = (tc0 + t)*16 + qm;
      float bias = (col < R) ? ebl[col] : 0.f;
      #pragma unroll
      for (int rg = 0; rg < 4; rg++){
        int row = tr*16 + quad*4 + rg;
        float v = (col < R) ? (acc[t][rg] + bias) : 0.f;
        if (col < R && row < R)
          Z1[(size_t)b*RR2 + row*R + col] = f2bf(v);
        ssv[rg] += v; sqv[rg] += v*v;
      }
    }
    #pragma unroll
    for (int off = 1; off < 16; off <<= 1){
      #pragma unroll
      for (int rg = 0; rg < 4; rg++){
        ssv[rg] += __shfl_xor(ssv[rg], off, 64);
        sqv[rg] += __shfl_xor(sqv[rg], off, 64);
      }
    }
    if (qm == 0){
      int half = wave >> 3;
      #pragma unroll
      for (int rg = 0; rg < 4; rg++){
        int row = tr*16 + quad*4 + rg;
        zps[row*2 + half] = ssv[rg];
        zpq[row*2 + half] = sqv[rg];
      }
    }
  }

  // ---- X path partials: T1x = M @ X (M stable in bA); vectorized uint2 LDS reads ----
  const float* Xb = Xc + (size_t)b * R * 3;
  if (tid < R*4){
    int n = tid >> 2, part = tid & 3;
    const ushort_t* rowp = &bA[n*LS];
    float t0 = 0.f, t1 = 0.f, t2 = 0.f;
    for (int mb = part*4; mb < 116; mb += 16){
      uint2 w = *(const uint2*)(rowp + mb);
      float p0 = u2f_lo(w.x), p1 = u2f_hi(w.x), p2 = u2f_lo(w.y), p3 = u2f_hi(w.y);
      const float* x4 = Xb + mb*3;
      t0 = fmaf(p0, x4[0], fmaf(p1, x4[3], fmaf(p2, x4[6], fmaf(p3, x4[9],  t0))));
      t1 = fmaf(p0, x4[1], fmaf(p1, x4[4], fmaf(p2, x4[7], fmaf(p3, x4[10], t1))));
      t2 = fmaf(p0, x4[2], fmaf(p1, x4[5], fmaf(p2, x4[8], fmaf(p3, x4[11], t2))));
    }
    xp[tid*3+0] = t0; xp[tid*3+1] = t1; xp[tid*3+2] = t2;
  }
  __syncthreads();
  if (tid < R){
    float c0 = xp[tid*12+0] + xp[tid*12+3] + xp[tid*12+6] + xp[tid*12+9];
    float c1 = xp[tid*12+1] + xp[tid*12+4] + xp[tid*12+7] + xp[tid*12+10];
    float c2 = xp[tid*12+2] + xp[tid*12+5] + xp[tid*12+8] + xp[tid*12+11];
    float s = 0.f, q = 0.f;
    #pragma unroll
    for (int e = 0; e < 3; e++){
      float v = nbl[e] + c0*nwl[e*3+0] + c1*nwl[e*3+1] + c2*nwl[e*3+2];
      X1[((size_t)b*R + tid)*3 + e] = v;
      s += v; q += v*v;
    }
    atomicAdd(&xsumS[sh*STL + layer*R + tid], s);
    atomicAdd(&xsqS [sh*STL + layer*R + tid], q);
    atomicAdd(&zsumS[sh*STL + layer*R + tid], zps[tid*2] + zps[tid*2+1]);
    atomicAdd(&zsqS [sh*STL + layer*R + tid], zpq[tid*2] + zpq[tid*2+1]);
  }
}

// ---------------- apply BN (in place) to all XZ feature slots, t=0..4, one pass ----------------
// (byte-identical to the round-6 passing version)
__global__ void k_applyAll(const float* __restrict__ dnS, const float* __restrict__ deS,
                           const float* __restrict__ dng, const float* __restrict__ dnbe,
                           const float* __restrict__ deg, const float* __restrict__ debe,
                           ushort_t* __restrict__ XZ)
{
  int idx = blockIdx.x * 256 + threadIdx.x;    // BATCH*R
  int bi = idx / R, r = idx - bi*R;
  const float cn = (float)(BATCH * R);
  const float ce = (float)(BATCH * R * 3);
  #pragma unroll
  for (int t = 0; t < 5; t++){
    float dns = 0.f, dnq = 0.f, des = 0.f, deq = 0.f;
    #pragma unroll
    for (int s2 = 0; s2 < NSH; s2++){
      dns += dnS[s2*10 + t*2+0]; dnq += dnS[s2*10 + t*2+1];
      des += deS[s2*10 + t*2+0]; deq += deS[s2*10 + t*2+1];
    }
    float mn = dns / cn;
    float vn = fmaxf(dnq / cn - mn*mn, 0.f);
    size_t sn = (size_t)bi*XZS + t*R + r;
    float hn = (bf2f(XZ[sn]) - mn) * rsqrtf(vn + EPSF) * dng[t] + dnbe[t];
    XZ[sn] = f2bf(hn);
    float me = des / ce;
    float ve = fmaxf(deq / ce - me*me, 0.f);
    float rse = rsqrtf(ve + EPSF);
    size_t se = (size_t)bi*XZS + 5*R + t*3*R + r*3;
    #pragma unroll
    for (int p = 0; p < 3; p++){
      float he = (bf2f(XZ[se+p]) - me) * rse * deg[t] + debe[t];
      XZ[se+p] = f2bf(he);
    }
  }
}

// ---------------- classifier: fc1 MFMA GEMM with fused fc2 reduction ----------------
// (byte-identical to the round-6 passing version)
__launch_bounds__(256)
__global__ void k_fc(const ushort_t* __restrict__ XZ, const ushort_t* __restrict__ cw1p,
                     const float* __restrict__ cb1, const float* __restrict__ cw2,
                     float* __restrict__ out){
  const int tid  = threadIdx.x;
  const int lane = tid & 63;
  const int wave = tid >> 6;
  const int qm   = lane & 15;
  const int quad = lane >> 4;
  const int m0   = blockIdx.x * 64 + wave * 16;
  const int n0   = blockIdx.y * 64;

  const f32x4 vzero = {0.f, 0.f, 0.f, 0.f};
  f32x4 acc[4];
  #pragma unroll
  for (int t = 0; t < 4; t++) acc[t] = vzero;

  const ushort_t* arow = XZ + (size_t)(m0 + qm) * XZS;
  for (int kk = 0; kk < XZS; kk += 32){
    bf16x8 a = *(const bf16x8*)(arow + kk + quad*8);
    #pragma unroll
    for (int t = 0; t < 4; t++){
      const ushort_t* brow = cw1p + (size_t)(n0 + t*16 + qm) * XZS;
      bf16x8 bf = *(const bf16x8*)(brow + kk + quad*8);
      acc[t] = __builtin_amdgcn_mfma_f32_16x16x32_bf16(a, bf, acc[t], 0, 0, 0);
    }
  }
  // fused fc2: h = relu(acc + cb1); partial dot with cw2 rows; qm-reduce; atomic out
  #pragma unroll
  for (int rg = 0; rg < 4; rg++){
    float p0 = 0.f, p1 = 0.f;
    #pragma unroll
    for (int t = 0; t < 4; t++){
      int n = n0 + t*16 + qm;
      float h = fmaxf(acc[t][rg] + cb1[n], 0.f);
      p0 = fmaf(h, cw2[n], p0);
      p1 = fmaf(h, cw2[1024 + n], p1);
    }
    #pragma unroll
    for (int o = 1; o < 16; o <<= 1){
      p0 += __shfl_xor(p0, o, 64);
      p1 += __shfl_xor(p1, o, 64);
    }
    if (qm == 0){
      int m = m0 + quad*4 + rg;
      atomicAdd(&out[m*2 + 0], p0);
      atomicAdd(&out[m*2 + 1], p1);
    }
  }
}

extern "C" void kernel_launch(void* const* d_in, const int* in_sizes, int n_in,
                              void* d_out, int out_size, void* d_ws, size_t ws_size,
                              hipStream_t stream)
{
  const float* Xin  = (const float*)d_in[0];
  const float* Zin  = (const float*)d_in[1];
  const float* aw1  = (const float*)d_in[2];
  const float* ab1  = (const float*)d_in[3];
  const float* aw2  = (const float*)d_in[4];
  const float* ab2  = (const float*)d_in[5];
  const float* nw   = (const float*)d_in[6];
  const float* nb   = (const float*)d_in[7];
  const float* ew   = (const float*)d_in[8];
  const float* eb   = (const float*)d_in[9];
  const float* gng  = (const float*)d_in[10];
  const float* gnb  = (const float*)d_in[11];
  const float* geg  = (const float*)d_in[12];
  const float* geb  = (const float*)d_in[13];
  const float* dnw  = (const float*)d_in[14];
  const float* dnb  = (const float*)d_in[15];
  const float* dng  = (const float*)d_in[16];
  const float* dnbe = (const float*)d_in[17];
  const float* dew  = (const float*)d_in[18];
  const float* deb  = (const float*)d_in[19];
  const float* deg  = (const float*)d_in[20];
  const float* debe = (const float*)d_in[21];
  const float* cw1  = (const float*)d_in[22];
  const float* cb1  = (const float*)d_in[23];
  const float* cw2  = (const float*)d_in[24];
  const float* cb2  = (const float*)d_in[25];

  // ---- workspace layout (total 67,857,024 B < 69,605,444 B proven addressable) ----
  ushort_t* Zc = (ushort_t*)d_ws;            // bf16 Z state
  ushort_t* Z1 = Zc + NZ_ELEM;               // bf16 pre-BN Z1
  float*    Xc = (float*)(Z1 + NZ_ELEM);     // fp32 X state
  float*    X1 = Xc + NX_ELEM;               // fp32 pre-BN X1
  ushort_t* XZ = (ushort_t*)(X1 + NX_ELEM);  // bf16 features (B,XZS)
  float*    st = (float*)(XZ + BATCH*XZS);   // stats: 15008 floats (sharded)
  float* zsumS = st;               // [NSH][STL]
  float* zsqS  = st + 3712;
  float* xsumS = st + 7424;
  float* xsqS  = st + 11136;
  float* dnS   = st + 14848;       // [NSH][10]
  float* deS   = st + 14928;       // [NSH][10]
  ushort_t* aw2p = (ushort_t*)(st + 15008);
  ushort_t* ewp  = aw2p + 4*16384;
  ushort_t* cw1p = ewp + 4*16384;

  float* outp = (float*)d_out;

  // merged init (also seeds out = cb2 for the fused-fc atomic accumulation)
  k_init<<<4096, 256, 0, stream>>>((const float4*)Zin, (uint4*)Zc, Xin, Xc,
                                   st, (unsigned*)XZ, (unsigned*)Z1,
                                   aw2, ew, aw2p, ewp, cw1, cw1p, cb2, outp);

  // fused layers (layer i prologue = BN/residual of layer i-1 + snapshot t=i; then attn i)
  for (int i = 0; i < NL; i++){
    k_fused<<<BATCH, 1024, 0, stream>>>(Xc, Zc, Z1, X1, aw1, ab1, aw2p, ab2,
                                        nw, nb, ewp, eb, zsumS, zsqS, xsumS, xsqS,
                                        geg, geb, gng, gnb, dnw, dnb, dew, deb,
                                        XZ, dnS, deS, i, 1);
  }
  // tail: BN/residual of layer 3 + snapshot t=4, no attention
  k_fused<<<BATCH, 1024, 0, stream>>>(Xc, Zc, Z1, X1, aw1, ab1, aw2p, ab2,
                                      nw, nb, ewp, eb, zsumS, zsqS, xsumS, xsqS,
                                      geg, geb, gng, gnb, dnw, dnb, dew, deb,
                                      XZ, dnS, deS, NL, 0);

  k_applyAll<<<464, 256, 0, stream>>>(dnS, deS, dng, dnbe, deg, debe, XZ);

  k_fc<<<dim3(16, 16), 256, 0, stream>>>(XZ, cw1p, cb1, cw2, outp);
}

// Round 10
// 650.862 us; speedup vs baseline: 1.8625x; 1.0035x over previous
//
#include <hip/hip_runtime.h>
#if __has_include(<hip/hip_bf16.h>)
#include <hip/hip_bf16.h>
#define HAVE_HIP_BF16 1
#endif

#define R 116
#define BATCH 1024
#define NL 4
#define RR2 13456          // R*R
#define EPSF 1e-5f
#define NZ_ELEM (BATCH * RR2)     // 13,778,944
#define NX_ELEM (BATCH * R * 3)   //    356,352
#define LS 136                    // LDS row stride (bf16 elems)
#define XZS 2336                  // XZ/cw1p K-stride: 2320 padded to 73*32
#define NSH 8                     // stat shards (atomic contention divider)
#define STL 464                   // NL*R stats stride
#define NCH 1682                  // RR2/8 uint4 chunks per graph

typedef unsigned short ushort_t;
typedef __attribute__((ext_vector_type(8))) short bf16x8;
typedef __attribute__((ext_vector_type(4))) float f32x4;

__device__ __forceinline__ float bf2f(unsigned short u){
  union { unsigned int i; float f; } v; v.i = ((unsigned int)u) << 16; return v.f;
}
// f32 -> bf16 RTNE.  HW path uses the OFFICIAL intrinsic (m240: scalar cast, compiler
// may fuse pairs into v_cvt_pk itself).  Hand-written v_cvt_pk asm remains QUARANTINED
// (rounds 5/8: absmax 1.41).  Fallback = proven manual RTNE sequence (bit-identical).
__device__ __forceinline__ unsigned short f2bf(float f){
#ifdef HAVE_HIP_BF16
  union { __hip_bfloat16 h; unsigned short u; } cv;
  cv.h = __float2bfloat16(f);
  return cv.u;
#else
  union { float ff; unsigned int i; } v; v.ff = f;
  return (unsigned short)((v.i + 0x7fffu + ((v.i >> 16) & 1u)) >> 16);
#endif
}
// bf16 pair unpack from one dword: 1 VALU op each
__device__ __forceinline__ float u2f_lo(unsigned w){
  union { unsigned i; float f; } v; v.i = w << 16; return v.f;
}
__device__ __forceinline__ float u2f_hi(unsigned w){
  union { unsigned i; float f; } v; v.i = w & 0xffff0000u; return v.f;
}
__device__ __forceinline__ float wsum(float v){
  #pragma unroll
  for (int o = 32; o > 0; o >>= 1) v += __shfl_xor(v, o, 64);
  return v;
}
__device__ __forceinline__ float wmaxr(float v){
  #pragma unroll
  for (int o = 32; o > 0; o >>= 1) v = fmaxf(v, __shfl_xor(v, o, 64));
  return v;
}
// 16B bf16 fragment load from an 8B-aligned global address (Z rows have 232B stride)
__device__ __forceinline__ bf16x8 ldg_z8(const ushort_t* p){
  union { uint2 u2[2]; bf16x8 v; } c;
  c.u2[0] = *(const uint2*)p;
  c.u2[1] = *(const uint2*)(p + 4);
  return c.v;
}

// ---------------- merged init: Z conv, cw1/aw2/ew pack, X copy, zeroing, out=cb2 ----------------
__global__ void k_init(const float4* __restrict__ Zin, uint4* __restrict__ Zc8,
                       const float* __restrict__ Xin, float* __restrict__ Xc,
                       float* __restrict__ st, unsigned* __restrict__ xzw,
                       unsigned* __restrict__ z1g,
                       const float* __restrict__ aw2, const float* __restrict__ ew,
                       ushort_t* __restrict__ aw2p, ushort_t* __restrict__ ewp,
                       const float* __restrict__ cw1, ushort_t* __restrict__ cw1p,
                       const float* __restrict__ cb2, float* __restrict__ out)
{
  int idx = blockIdx.x * 256 + threadIdx.x;
  int stride = gridDim.x * 256;
  for (int i = idx; i < NZ_ELEM/8; i += stride){
    float4 a = Zin[2*i], b = Zin[2*i+1];
    uint4 w;
    w.x = (unsigned)f2bf(a.x) | ((unsigned)f2bf(a.y) << 16);
    w.y = (unsigned)f2bf(a.z) | ((unsigned)f2bf(a.w) << 16);
    w.z = (unsigned)f2bf(b.x) | ((unsigned)f2bf(b.y) << 16);
    w.w = (unsigned)f2bf(b.z) | ((unsigned)f2bf(b.w) << 16);
    Zc8[i] = w;
  }
  for (int i = idx; i < 1024 * XZS; i += stride){
    int n = i / XZS, k = i - n * XZS;
    cw1p[i] = (k < 2320) ? f2bf(cw1[n*2320 + k]) : (ushort_t)0;
  }
  for (int i = idx; i < 4*128*128; i += stride){
    int l = i >> 14, rem = i & 16383, row = rem >> 7, col = rem & 127;
    ushort_t v = 0, w = 0;
    if (row < R && col < R){
      v = f2bf(aw2[l*RR2 + col*R + row]);   // aw2p[row][col] = aw2[col][row]  (aw2^T)
      w = f2bf(ew [l*RR2 + row*R + col]);   // ewp [row][col] = ew[row][col]
    }
    aw2p[i] = v;
    ewp [i] = w;
  }
  for (int i = idx; i < NX_ELEM; i += stride) Xc[i] = Xin[i];
  for (int i = idx; i < 15008; i += stride) st[i] = 0.f;
  for (int i = idx; i < BATCH*XZS/2; i += stride) xzw[i] = 0u;
  for (int i = idx; i < 704; i += stride) z1g[i] = 0u;   // guard: graph 1023 row-tail reads
  for (int i = idx; i < 1024; i += stride){ out[2*i] = cb2[0]; out[2*i+1] = cb2[1]; }
}

// ==================================================================================
// Fused per-layer kernel.  Round-9 passing base + (1) HW bf16 cvt via intrinsic,
// (2) P0 2-chunk unroll with all 4 global loads issued before compute,
// (3) tail dispatch (with_attn==0) skips dead Zc/Xc write-backs.
// ==================================================================================
__launch_bounds__(1024, 8)
__global__ void k_fused(float* __restrict__ Xc, ushort_t* __restrict__ Zc,
                        ushort_t* __restrict__ Z1, float* __restrict__ X1,
                        const float* __restrict__ aw1, const float* __restrict__ ab1,
                        const ushort_t* __restrict__ aw2p, const float* __restrict__ ab2,
                        const float* __restrict__ nw,  const float* __restrict__ nb,
                        const ushort_t* __restrict__ ewp,  const float* __restrict__ eb,
                        float* __restrict__ zsumS, float* __restrict__ zsqS,
                        float* __restrict__ xsumS, float* __restrict__ xsqS,
                        const float* __restrict__ geg, const float* __restrict__ geb,
                        const float* __restrict__ gng, const float* __restrict__ gnb,
                        const float* __restrict__ dnw, const float* __restrict__ dnb,
                        const float* __restrict__ dew, const float* __restrict__ deb,
                        ushort_t* __restrict__ XZ,
                        float* __restrict__ dnS, float* __restrict__ deS,
                        int layer, int with_attn)
{
  __shared__ __align__(16) ushort_t bA[128*LS];    // P, then M (row-major)
  __shared__ __align__(16) ushort_t bB[128*LS];    // linear Z staging, then W, then E^T
  __shared__ float Ksm[3*R];
  __shared__ float ssm[R];
  __shared__ float xp[R*12];         // X-path partials; head aliased as BN coeffs in P0
  __shared__ float zps[128*2];       // per-row Z1 sum partials
  __shared__ float zpq[128*2];
  __shared__ float wsm[78];          // edge downsample weights
  __shared__ float xsred[3], xqred[3];
  __shared__ float zds[8], zqs[8];

  float* zcoA = xp;          // [R] BN coeff a for Z rows (dead before xp written)
  float* zcoC = xp + 116;
  float* xcoA = xp + 232;
  float* xcoC = xp + 348;
  ushort_t* bBlin = bB;      // linear staged Z view

  const int b    = blockIdx.x;
  const int tid  = threadIdx.x;
  const int lane = tid & 63;
  const int wave = tid >> 6;          // 16 waves
  const int qm   = lane & 15;
  const int quad = lane >> 4;
  const int tr   = wave & 7;
  const int tc0  = (wave >> 3) * 4;
  const int t_snap = layer;           // snapshot index for downsample outputs
  const int sh   = b & (NSH-1);

  ushort_t* Zb = Zc + (size_t)b * RR2;
  const ushort_t* Z1b = Z1 + (size_t)b * RR2;
  const float* ab2l = ab2 + layer * R;
  const float* ebl  = eb  + layer * R;
  const float* nwl  = nw  + layer * 9;
  const float* nbl  = nb  + layer * 3;
  const ushort_t* aw2l = aw2p + layer * 16384;
  const ushort_t* ewl  = ewp  + layer * 16384;

  const f32x4 vzero = {0.f, 0.f, 0.f, 0.f};

  // =============== Phase -1: per-row BN coeffs + wsm ===============
  if (tid < R){
    float a = 0.f, c = 0.f;
    if (layer > 0){
      const int pl = layer - 1;
      float ms = 0.f, qs = 0.f;
      #pragma unroll
      for (int s2 = 0; s2 < NSH; s2++){
        ms += zsumS[s2*STL + pl*R + tid];
        qs += zsqS [s2*STL + pl*R + tid];
      }
      const float cnt = (float)(BATCH * R);
      float m  = ms / cnt;
      float va = fmaxf(qs / cnt - m*m, 0.f);
      float rs = rsqrtf(va + EPSF);
      a = rs * geg[pl*R + tid];
      c = geb[pl*R + tid] - m * a;
    }
    zcoA[tid] = a; zcoC[tid] = c;
  } else if (tid >= 128 && tid < 128 + R){
    const int r = tid - 128;
    float a = 0.f, c = 0.f;
    if (layer > 0){
      const int pl = layer - 1;
      float ms = 0.f, qs = 0.f;
      #pragma unroll
      for (int s2 = 0; s2 < NSH; s2++){
        ms += xsumS[s2*STL + pl*R + r];
        qs += xsqS [s2*STL + pl*R + r];
      }
      const float cnt = (float)(BATCH * 3);
      float m  = ms / cnt;
      float va = fmaxf(qs / cnt - m*m, 0.f);
      float rs = rsqrtf(va + EPSF);
      a = rs * gng[pl*R + r];
      c = gnb[pl*R + r] - m * a;
    }
    xcoA[r] = a; xcoC[r] = c;
  } else if (tid >= 256 && tid < 256 + 78){
    wsm[tid - 256] = dew[t_snap*78 + (tid - 256)];
  }
  __syncthreads();   // ---- sync0 ----

  // =============== P0: full-width Z stream (2-chunk unroll) + X rows + bA pad zero ===============
  {
    const int ch0 = tid;                 // always < NCH (1682 > 1024)
    const int ch1 = tid + 1024;
    const bool hasB = (ch1 < NCH);
    const int e0A = ch0 << 3;
    const int e0B = ch1 << 3;
    // issue ALL global loads before any compute (2x MLP)
    uint4 zcA = *(const uint4*)(Zb + e0A);
    uint4 zcB; if (hasB) zcB = *(const uint4*)(Zb + e0B);
    if (layer > 0){
      uint4 z1A = *(const uint4*)(Z1b + e0A);
      uint4 z1B; if (hasB) z1B = *(const uint4*)(Z1b + e0B);
      #pragma unroll
      for (int half = 0; half < 2; half++){
        if (half == 1 && !hasB) break;
        const int e0 = half ? e0B : e0A;
        const uint4 zc4 = half ? zcB : zcA;
        const uint4 z14 = half ? z1B : z1A;
        const int r0 = e0 / 116;
        const int c0 = e0 - r0*116;      // %4==0; row crossing only at c0==112 (clean half split)
        float aA = zcoA[r0], cA = zcoC[r0];
        float aB = aA, cB = cA;
        if (c0 == 112){ aB = zcoA[r0+1]; cB = zcoC[r0+1]; }
        const unsigned zw[4]  = {zc4.x, zc4.y, zc4.z, zc4.w};
        const unsigned z1w[4] = {z14.x, z14.y, z14.z, z14.w};
        unsigned ow[4];
        #pragma unroll
        for (int h = 0; h < 4; h++){
          float aa = (h < 2) ? aA : aB;
          float cc = (h < 2) ? cA : cB;
          float vL = fmaxf(u2f_lo(z1w[h])*aa + cc, 0.f) + u2f_lo(zw[h]);
          float vH = fmaxf(u2f_hi(z1w[h])*aa + cc, 0.f) + u2f_hi(zw[h]);
          ow[h] = (unsigned)f2bf(vL) | ((unsigned)f2bf(vH) << 16);
        }
        uint4 o; o.x = ow[0]; o.y = ow[1]; o.z = ow[2]; o.w = ow[3];
        if (with_attn) *(uint4*)(Zb + e0) = o;   // residual state write-back (dead after tail)
        *(uint4*)&bBlin[e0] = o;                 // linear staging for downsample
      }
    } else {
      *(uint4*)&bBlin[e0A] = zcA;                // raw Z for t=0 snapshot (bit-identical)
      if (hasB) *(uint4*)&bBlin[e0B] = zcB;
    }
  }
  // X rows on threads 658-773 (they had only 1 Z chunk)
  {
    float fv = 0.f;
    if (tid >= 658 && tid < 658 + R){
      const int u = tid - 658;
      float* xcr = Xc + ((size_t)b*R + u)*3;
      float v0, v1, v2;
      if (layer > 0){
        float a = xcoA[u], c = xcoC[u];
        const float* x1r = X1 + ((size_t)b*R + u)*3;
        v0 = fmaxf(x1r[0]*a + c, 0.f) + xcr[0];
        v1 = fmaxf(x1r[1]*a + c, 0.f) + xcr[1];
        v2 = fmaxf(x1r[2]*a + c, 0.f) + xcr[2];
        if (with_attn){ xcr[0] = v0; xcr[1] = v1; xcr[2] = v2; }   // dead after tail
      } else {
        v0 = xcr[0]; v1 = xcr[1]; v2 = xcr[2];
      }
      if (with_attn){
        const float* aw1l = aw1 + layer * 9;
        const float* ab1l = ab1 + layer * 3;
        #pragma unroll
        for (int o = 0; o < 3; o++)
          Ksm[o*R + u] = ab1l[o] + aw1l[o*3+0]*v0 + aw1l[o*3+1]*v1 + aw1l[o*3+2]*v2;
      }
      float f = fmaxf(dnw[t_snap*3+0]*v0 + dnw[t_snap*3+1]*v1 + dnw[t_snap*3+2]*v2 + dnb[t_snap], 0.f);
      XZ[(size_t)b*XZS + t_snap*R + u] = f2bf(f);
      fv = f;
    }
    if (wave >= 10 && wave <= 12){
      float s = wsum(fv), q = wsum(fv*fv);
      if (lane == 0){ xsred[wave - 10] = s; xqred[wave - 10] = q; }
    }
  }
  // bA pad zeroing (rows 116-127 full; cols 116-135 of rows <116) on threads 774+
  if (tid >= 774){
    for (int i = tid - 774; i < 12*LS; i += 250) bA[116*LS + i] = 0;
    for (int i = tid - 774; i < 116*20; i += 250){
      int r = i/20, c = 116 + (i - r*20);
      bA[r*LS + c] = 0;
    }
  }
  __syncthreads();   // ---- sync1 ----

  // =============== P1: softmax (waves 0-9) || edge downsample (waves 10-15) ===============
  if (wave < 10){
    if (tid == 0){
      atomicAdd(&dnS[sh*10 + t_snap*2+0], xsred[0] + xsred[1] + xsred[2]);
      atomicAdd(&dnS[sh*10 + t_snap*2+1], xqred[0] + xqred[1] + xqred[2]);
    }
    if (with_attn){
      for (int n = wave; n < R; n += 10){
        float k0 = Ksm[n], k1 = Ksm[R+n], k2 = Ksm[2*R+n];
        int m0 = lane, m1 = lane + 64;
        float a0 = k0*Ksm[m0] + k1*Ksm[R+m0] + k2*Ksm[2*R+m0];
        float a1 = (m1 < R) ? (k0*Ksm[m1] + k1*Ksm[R+m1] + k2*Ksm[2*R+m1]) : -1e30f;
        float mx = wmaxr(fmaxf(a0, a1));
        float e0 = __expf(a0 - mx);
        float e1 = (m1 < R) ? __expf(a1 - mx) : 0.f;
        float sm = wsum(e0 + e1);
        float sab = wsum(e0 * ab2l[m0] + ((m1 < R) ? e1 * ab2l[m1] : 0.f));
        float inv = 1.f / sm;
        bA[n*LS + m0] = f2bf(e0 * inv);
        if (m1 < R) bA[n*LS + m1] = f2bf(e1 * inv);
        if (lane == 0) ssm[n] = sab * inv;
      }
    }
  } else {
    const int u = tid - 640;          // 0..383; 348 active
    float f = 0.f;
    if (u < 348){
      int r = u / 3, w = u - 3*r;
      int jlo = (w == 0) ? 39 : 0;
      int jhi = (w == 2) ? 77 : 78;
      int off = (w - 1) * 39;
      const ushort_t* vr = &bBlin[r*116];
      float acc = 0.f;
      for (int j = jlo; j < jhi; j++) acc += wsm[j] * bf2f(vr[j + off]);
      f = fmaxf(acc + deb[t_snap], 0.f);
      XZ[(size_t)b*XZS + 5*R + t_snap*3*R + r*3 + w] = f2bf(f);
    }
    float s = wsum(f), q = wsum(f*f);
    if (lane == 0){ zds[wave - 10] = s; zqs[wave - 10] = q; }
  }
  __syncthreads();   // ---- sync2 ----

  if (tid == 0){
    float ss = 0.f, qq = 0.f;
    #pragma unroll
    for (int k = 0; k < 6; k++){ ss += zds[k]; qq += zqs[k]; }
    atomicAdd(&deS[sh*10 + t_snap*2+0], ss);
    atomicAdd(&deS[sh*10 + t_snap*2+1], qq);
  }
  if (!with_attn) return;

  // ---- Stage A: W^T-product = aw2^T @ P^T; transposed-packed write -> bB = W row-major ----
  {
    f32x4 acc[4];
    #pragma unroll
    for (int t = 0; t < 4; t++) acc[t] = vzero;
    for (int kk = 0; kk < 128; kk += 32){
      bf16x8 a = *(const bf16x8*)(aw2l + (tr*16 + qm)*128 + kk + quad*8);
      #pragma unroll
      for (int t = 0; t < 4; t++){
        bf16x8 bf = *(const bf16x8*)&bA[((tc0 + t)*16 + qm)*LS + kk + quad*8];
        acc[t] = __builtin_amdgcn_mfma_f32_16x16x32_bf16(a, bf, acc[t], 0, 0, 0);
      }
    }
    const int r0 = tr*16 + quad*4;
    #pragma unroll
    for (int t = 0; t < 4; t++){
      int nn = (tc0 + t)*16 + qm;
      uint2 w;
      w.x = (unsigned)f2bf(acc[t][0]) | ((unsigned)f2bf(acc[t][1]) << 16);
      w.y = (unsigned)f2bf(acc[t][2]) | ((unsigned)f2bf(acc[t][3]) << 16);
      *(uint2*)&bB[nn*LS + r0] = w;
    }
  }
  __syncthreads();

  // ---- Stage B': M^T = W @ Z^T (+ssm); Z fragments from global; transposed write -> bA = M ----
  {
    f32x4 acc[4];
    #pragma unroll
    for (int t = 0; t < 4; t++) acc[t] = vzero;
    for (int kk = 0; kk < 128; kk += 32){
      bf16x8 a = *(const bf16x8*)&bB[(tr*16 + qm)*LS + kk + quad*8];
      #pragma unroll
      for (int t = 0; t < 4; t++){
        int nn = (tc0 + t)*16 + qm;
        bf16x8 bf = ldg_z8(Zb + nn*R + kk + quad*8);
        acc[t] = __builtin_amdgcn_mfma_f32_16x16x32_bf16(a, bf, acc[t], 0, 0, 0);
      }
    }
    const int r0 = tr*16 + quad*4;
    float s0 = 0.f, s1 = 0.f, s2 = 0.f, s3 = 0.f;
    if (r0 < R){ s0 = ssm[r0]; s1 = ssm[r0+1]; s2 = ssm[r0+2]; s3 = ssm[r0+3]; }
    #pragma unroll
    for (int t = 0; t < 4; t++){
      int nn = (tc0 + t)*16 + qm;
      uint2 w;
      w.x = (unsigned)f2bf(acc[t][0] + s0) | ((unsigned)f2bf(acc[t][1] + s1) << 16);
      w.y = (unsigned)f2bf(acc[t][2] + s2) | ((unsigned)f2bf(acc[t][3] + s3) << 16);
      *(uint2*)&bA[nn*LS + r0] = w;
    }
  }
  __syncthreads();

  // ---- Stage E: E = Z @ ew^T; transposed write -> bB = E^T row-major (overwrites W) ----
  {
    f32x4 acc[4];
    #pragma unroll
    for (int t = 0; t < 4; t++) acc[t] = vzero;
    for (int kk = 0; kk < 128; kk += 32){
      bf16x8 a = ldg_z8(Zb + (tr*16 + qm)*R + kk + quad*8);
      #pragma unroll
      for (int t = 0; t < 4; t++){
        bf16x8 bf = *(const bf16x8*)(ewl + ((tc0 + t)*16 + qm)*128 + kk + quad*8);
        acc[t] = __builtin_amdgcn_mfma_f32_16x16x32_bf16(a, bf, acc[t], 0, 0, 0);
      }
    }
    const int r0 = tr*16 + quad*4;
    #pragma unroll
    for (int t = 0; t < 4; t++){
      int nn = (tc0 + t)*16 + qm;
      uint2 w;
      w.x = (unsigned)f2bf(acc[t][0]) | ((unsigned)f2bf(acc[t][1]) << 16);
      w.y = (unsigned)f2bf(acc[t][2]) | ((unsigned)f2bf(acc[t][3]) << 16);
      *(uint2*)&bB[nn*LS + r0] = w;
    }
  }
  __syncthreads();

  // ---- Stage D: Z1 = M @ E + eb -> global bf16; row stats -> LDS partials ----
  {
    f32x4 acc[4];
    #pragma unroll
    for (int t = 0; t < 4; t++) acc[t] = vzero;
    for (int kk = 0; kk < 128; kk += 32){
      bf16x8 a = *(const bf16x8*)&bA[(tr*16 + qm)*LS + kk + quad*8];
      #pragma unroll
      for (int t = 0; t < 4; t++){
        bf16x8 bf = *(const bf16x8*)&bB[((tc0 + t)*16 + qm)*LS + kk + quad*8];
        acc[t] = __builtin_amdgcn_mfma_f32_16x16x32_bf16(a, bf, acc[t], 0, 0, 0);
      }
    }
    float ssv[4] = {0.f,0.f,0.f,0.f}, sqv[4] = {0.f,0.f,0.f,0.f};
    #pragma unroll
    for (int t = 0; t < 4; t++){
      int col = (tc0 + t)*16 + qm;
      float bias = (col < R) ? ebl[col] : 0.f;
      #pragma unroll
      for (int rg = 0; rg < 4; rg++){
        int row = tr*16 + quad*4 + rg;
        float v = (col < R) ? (acc[t][rg] + bias) : 0.f;
        if (col < R && row < R)
          Z1[(size_t)b*RR2 + row*R + col] = f2bf(v);
        ssv[rg] += v; sqv[rg] += v*v;
      }
    }
    #pragma unroll
    for (int off = 1; off < 16; off <<= 1){
      #pragma unroll
      for (int rg = 0; rg < 4; rg++){
        ssv[rg] += __shfl_xor(ssv[rg], off, 64);
        sqv[rg] += __shfl_xor(sqv[rg], off, 64);
      }
    }
    if (qm == 0){
      int half = wave >> 3;
      #pragma unroll
      for (int rg = 0; rg < 4; rg++){
        int row = tr*16 + quad*4 + rg;
        zps[row*2 + half] = ssv[rg];
        zpq[row*2 + half] = sqv[rg];
      }
    }
  }

  // ---- X path partials: T1x = M @ X (M stable in bA); vectorized uint2 LDS reads ----
  const float* Xb = Xc + (size_t)b * R * 3;
  if (tid < R*4){
    int n = tid >> 2, part = tid & 3;
    const ushort_t* rowp = &bA[n*LS];
    float t0 = 0.f, t1 = 0.f, t2 = 0.f;
    for (int mb = part*4; mb < 116; mb += 16){
      uint2 w = *(const uint2*)(rowp + mb);
      float p0 = u2f_lo(w.x), p1 = u2f_hi(w.x), p2 = u2f_lo(w.y), p3 = u2f_hi(w.y);
      const float* x4 = Xb + mb*3;
      t0 = fmaf(p0, x4[0], fmaf(p1, x4[3], fmaf(p2, x4[6], fmaf(p3, x4[9],  t0))));
      t1 = fmaf(p0, x4[1], fmaf(p1, x4[4], fmaf(p2, x4[7], fmaf(p3, x4[10], t1))));
      t2 = fmaf(p0, x4[2], fmaf(p1, x4[5], fmaf(p2, x4[8], fmaf(p3, x4[11], t2))));
    }
    xp[tid*3+0] = t0; xp[tid*3+1] = t1; xp[tid*3+2] = t2;
  }
  __syncthreads();
  if (tid < R){
    float c0 = xp[tid*12+0] + xp[tid*12+3] + xp[tid*12+6] + xp[tid*12+9];
    float c1 = xp[tid*12+1] + xp[tid*12+4] + xp[tid*12+7] + xp[tid*12+10];
    float c2 = xp[tid*12+2] + xp[tid*12+5] + xp[tid*12+8] + xp[tid*12+11];
    float s = 0.f, q = 0.f;
    #pragma unroll
    for (int e = 0; e < 3; e++){
      float v = nbl[e] + c0*nwl[e*3+0] + c1*nwl[e*3+1] + c2*nwl[e*3+2];
      X1[((size_t)b*R + tid)*3 + e] = v;
      s += v; q += v*v;
    }
    atomicAdd(&xsumS[sh*STL + layer*R + tid], s);
    atomicAdd(&xsqS [sh*STL + layer*R + tid], q);
    atomicAdd(&zsumS[sh*STL + layer*R + tid], zps[tid*2] + zps[tid*2+1]);
    atomicAdd(&zsqS [sh*STL + layer*R + tid], zpq[tid*2] + zpq[tid*2+1]);
  }
}

// ---------------- apply BN (in place) to all XZ feature slots, t=0..4, one pass ----------------
__global__ void k_applyAll(const float* __restrict__ dnS, const float* __restrict__ deS,
                           const float* __restrict__ dng, const float* __restrict__ dnbe,
                           const float* __restrict__ deg, const float* __restrict__ debe,
                           ushort_t* __restrict__ XZ)
{
  int idx = blockIdx.x * 256 + threadIdx.x;    // BATCH*R
  int bi = idx / R, r = idx - bi*R;
  const float cn = (float)(BATCH * R);
  const float ce = (float)(BATCH * R * 3);
  #pragma unroll
  for (int t = 0; t < 5; t++){
    float dns = 0.f, dnq = 0.f, des = 0.f, deq = 0.f;
    #pragma unroll
    for (int s2 = 0; s2 < NSH; s2++){
      dns += dnS[s2*10 + t*2+0]; dnq += dnS[s2*10 + t*2+1];
      des += deS[s2*10 + t*2+0]; deq += deS[s2*10 + t*2+1];
    }
    float mn = dns / cn;
    float vn = fmaxf(dnq / cn - mn*mn, 0.f);
    size_t sn = (size_t)bi*XZS + t*R + r;
    float hn = (bf2f(XZ[sn]) - mn) * rsqrtf(vn + EPSF) * dng[t] + dnbe[t];
    XZ[sn] = f2bf(hn);
    float me = des / ce;
    float ve = fmaxf(deq / ce - me*me, 0.f);
    float rse = rsqrtf(ve + EPSF);
    size_t se = (size_t)bi*XZS + 5*R + t*3*R + r*3;
    #pragma unroll
    for (int p = 0; p < 3; p++){
      float he = (bf2f(XZ[se+p]) - me) * rse * deg[t] + debe[t];
      XZ[se+p] = f2bf(he);
    }
  }
}

// ---------------- classifier: fc1 MFMA GEMM with fused fc2 reduction ----------------
__launch_bounds__(256)
__global__ void k_fc(const ushort_t* __restrict__ XZ, const ushort_t* __restrict__ cw1p,
                     const float* __restrict__ cb1, const float* __restrict__ cw2,
                     float* __restrict__ out){
  const int tid  = threadIdx.x;
  const int lane = tid & 63;
  const int wave = tid >> 6;
  const int qm   = lane & 15;
  const int quad = lane >> 4;
  const int m0   = blockIdx.x * 64 + wave * 16;
  const int n0   = blockIdx.y * 64;

  const f32x4 vzero = {0.f, 0.f, 0.f, 0.f};
  f32x4 acc[4];
  #pragma unroll
  for (int t = 0; t < 4; t++) acc[t] = vzero;

  const ushort_t* arow = XZ + (size_t)(m0 + qm) * XZS;
  for (int kk = 0; kk < XZS; kk += 32){
    bf16x8 a = *(const bf16x8*)(arow + kk + quad*8);
    #pragma unroll
    for (int t = 0; t < 4; t++){
      const ushort_t* brow = cw1p + (size_t)(n0 + t*16 + qm) * XZS;
      bf16x8 bf = *(const bf16x8*)(brow + kk + quad*8);
      acc[t] = __builtin_amdgcn_mfma_f32_16x16x32_bf16(a, bf, acc[t], 0, 0, 0);
    }
  }
  // fused fc2: h = relu(acc + cb1); partial dot with cw2 rows; qm-reduce; atomic out
  #pragma unroll
  for (int rg = 0; rg < 4; rg++){
    float p0 = 0.f, p1 = 0.f;
    #pragma unroll
    for (int t = 0; t < 4; t++){
      int n = n0 + t*16 + qm;
      float h = fmaxf(acc[t][rg] + cb1[n], 0.f);
      p0 = fmaf(h, cw2[n], p0);
      p1 = fmaf(h, cw2[1024 + n], p1);
    }
    #pragma unroll
    for (int o = 1; o < 16; o <<= 1){
      p0 += __shfl_xor(p0, o, 64);
      p1 += __shfl_xor(p1, o, 64);
    }
    if (qm == 0){
      int m = m0 + quad*4 + rg;
      atomicAdd(&out[m*2 + 0], p0);
      atomicAdd(&out[m*2 + 1], p1);
    }
  }
}

extern "C" void kernel_launch(void* const* d_in, const int* in_sizes, int n_in,
                              void* d_out, int out_size, void* d_ws, size_t ws_size,
                              hipStream_t stream)
{
  const float* Xin  = (const float*)d_in[0];
  const float* Zin  = (const float*)d_in[1];
  const float* aw1  = (const float*)d_in[2];
  const float* ab1  = (const float*)d_in[3];
  const float* aw2  = (const float*)d_in[4];
  const float* ab2  = (const float*)d_in[5];
  const float* nw   = (const float*)d_in[6];
  const float* nb   = (const float*)d_in[7];
  const float* ew   = (const float*)d_in[8];
  const float* eb   = (const float*)d_in[9];
  const float* gng  = (const float*)d_in[10];
  const float* gnb  = (const float*)d_in[11];
  const float* geg  = (const float*)d_in[12];
  const float* geb  = (const float*)d_in[13];
  const float* dnw  = (const float*)d_in[14];
  const float* dnb  = (const float*)d_in[15];
  const float* dng  = (const float*)d_in[16];
  const float* dnbe = (const float*)d_in[17];
  const float* dew  = (const float*)d_in[18];
  const float* deb  = (const float*)d_in[19];
  const float* deg  = (const float*)d_in[20];
  const float* debe = (const float*)d_in[21];
  const float* cw1  = (const float*)d_in[22];
  const float* cb1  = (const float*)d_in[23];
  const float* cw2  = (const float*)d_in[24];
  const float* cb2  = (const float*)d_in[25];

  // ---- workspace layout (total 67,857,024 B < 69,605,444 B proven addressable) ----
  ushort_t* Zc = (ushort_t*)d_ws;            // bf16 Z state
  ushort_t* Z1 = Zc + NZ_ELEM;               // bf16 pre-BN Z1
  float*    Xc = (float*)(Z1 + NZ_ELEM);     // fp32 X state
  float*    X1 = Xc + NX_ELEM;               // fp32 pre-BN X1
  ushort_t* XZ = (ushort_t*)(X1 + NX_ELEM);  // bf16 features (B,XZS)
  float*    st = (float*)(XZ + BATCH*XZS);   // stats: 15008 floats (sharded)
  float* zsumS = st;               // [NSH][STL]
  float* zsqS  = st + 3712;
  float* xsumS = st + 7424;
  float* xsqS  = st + 11136;
  float* dnS   = st + 14848;       // [NSH][10]
  float* deS   = st + 14928;       // [NSH][10]
  ushort_t* aw2p = (ushort_t*)(st + 15008);
  ushort_t* ewp  = aw2p + 4*16384;
  ushort_t* cw1p = ewp + 4*16384;

  float* outp = (float*)d_out;

  // merged init (also seeds out = cb2 for the fused-fc atomic accumulation)
  k_init<<<4096, 256, 0, stream>>>((const float4*)Zin, (uint4*)Zc, Xin, Xc,
                                   st, (unsigned*)XZ, (unsigned*)Z1,
                                   aw2, ew, aw2p, ewp, cw1, cw1p, cb2, outp);

  // fused layers (layer i prologue = BN/residual of layer i-1 + snapshot t=i; then attn i)
  for (int i = 0; i < NL; i++){
    k_fused<<<BATCH, 1024, 0, stream>>>(Xc, Zc, Z1, X1, aw1, ab1, aw2p, ab2,
                                        nw, nb, ewp, eb, zsumS, zsqS, xsumS, xsqS,
                                        geg, geb, gng, gnb, dnw, dnb, dew, deb,
                                        XZ, dnS, deS, i, 1);
  }
  // tail: BN/residual of layer 3 + snapshot t=4, no attention (skips dead Zc/Xc writes)
  k_fused<<<BATCH, 1024, 0, stream>>>(Xc, Zc, Z1, X1, aw1, ab1, aw2p, ab2,
                                      nw, nb, ewp, eb, zsumS, zsqS, xsumS, xsqS,
                                      geg, geb, gng, gnb, dnw, dnb, dew, deb,
                                      XZ, dnS, deS, NL, 0);

  k_applyAll<<<464, 256, 0, stream>>>(dnS, deS, dng, dnbe, deg, debe, XZ);

  k_fc<<<dim3(16, 16), 256, 0, stream>>>(XZ, cw1p, cb1, cw2, outp);
}